// Round 3
// baseline (1834.470 us; speedup 1.0000x reference)
//
#include <hip/hip_runtime.h>
#include <math.h>
#include <stdint.h>

// Problem constants (per batch): C=64, H=W=256, P=65536 pixels.
#define P_ 65536

// ---- per-batch workspace layout (float offsets). Peak = 33,423,360 floats
#define DW_OFF   0ul            // 192*P (q,k,v post-dwconv)
#define QKV_OFF  12582912ul     // 192*P (pre-dwconv)  [dead after dwconv]
#define ATTP_OFF QKV_OFF        // 64*P K-split partials ALIAS dead QKV region
#define Y_OFF    25165824ul     // 64*P  (attn out)
#define ATT_OFF  31457280ul     // P     (softmaxed attention)
// stage C overlays:
#define HID_OFF  0ul            // 340*P
#define G_OFF    22282240ul     // 170*P

typedef __attribute__((ext_vector_type(8))) short bf16x8;   // 8 bf16 in 4 VGPRs
typedef __attribute__((ext_vector_type(4))) float f32x4;

__device__ __forceinline__ unsigned short f2bf(float f) {   // RNE fp32->bf16
    uint32_t u = __float_as_uint(f);
    return (unsigned short)((u + 0x7FFFu + ((u >> 16) & 1u)) >> 16);
}
__device__ __forceinline__ float bf2f(unsigned short h) {
    return __uint_as_float((uint32_t)h << 16);
}

// ============== MFMA 1x1 conv: out[o,p] = sum_c W[o,c]*X[c,p] ===============
// PX-pixel tile per block, 256 threads = 4 waves. ALL weights (COPAD x CPAD
// bf16, swizzled) staged into LDS once; X tile staged once (+ optional LN).
// Compute loop over 64-o chunks runs with ZERO barriers.
// A-frag: A[m=lane&15][k=quad*8+j]; B-frag: B[k=quad*8+j][n=lane&15];
// D: row=(quad*4+reg) (o), col=lane&15 (px). fp32 epilogue: +bias [+res].
template<int CIN, int CPAD, int COUT, int COPAD, int PX, bool LN, bool RES>
__global__ __launch_bounds__(256) void conv_mfma_kernel(
        const float* __restrict__ in, const float* __restrict__ lnw,
        const float* __restrict__ lnb, const float* __restrict__ Wt,
        const float* __restrict__ bias, float* __restrict__ out,
        const float* __restrict__ res) {
    constexpr int NSL = CPAD / 32;           // K slices of 32
    constexpr int NPT = PX / 64;             // px sub-tiles per wave
    __shared__ unsigned short sX[PX * CPAD];
    __shared__ unsigned short sW[COPAD * CPAD];
    __shared__ float sPa[256], sPb[256], sMu[128], sInv[128];
    int tid = threadIdx.x;
    int hw0 = blockIdx.x * PX;
    int lane = tid & 63, wave = tid >> 6;

    {   // ---- stage X: fp32 global -> bf16 swizzled LDS [px][c] ----
        uint32_t* sX32 = (uint32_t*)sX;
        #pragma unroll
        for (int it = 0; it < PX * CPAD / 512; ++it) {
            int idx = tid + it * 256;
            int p = idx & (PX - 1), c = (idx / PX) * 2;
            float v0 = (c < CIN)     ? in[(size_t)c * P_ + hw0 + p]     : 0.f;
            float v1 = (c + 1 < CIN) ? in[(size_t)(c+1) * P_ + hw0 + p] : 0.f;
            uint32_t pk = (uint32_t)f2bf(v0) | ((uint32_t)f2bf(v1) << 16);
            int kb = c >> 3;
            sX32[(p * CPAD + (((kb ^ (p & 7)) << 3) | (c & 7))) >> 1] = pk;
        }
    }
    {   // ---- stage ALL weights: [o][c] bf16 swizzled (resident whole kernel)
        uint32_t* sW32 = (uint32_t*)sW;
        #pragma unroll
        for (int it = 0; it < COPAD * CPAD / 512; ++it) {
            int idx = tid + it * 256;
            int c2 = idx % (CPAD / 2), o = idx / (CPAD / 2);
            int c = c2 * 2;
            float v0 = (o < COUT && c < CIN)     ? Wt[(size_t)o * CIN + c]     : 0.f;
            float v1 = (o < COUT && c + 1 < CIN) ? Wt[(size_t)o * CIN + c + 1] : 0.f;
            uint32_t pk = (uint32_t)f2bf(v0) | ((uint32_t)f2bf(v1) << 16);
            int kb = c >> 3;
            sW32[(o * CPAD + (((kb ^ (o & 7)) << 3) | (c & 7))) >> 1] = pk;
        }
    }
    __syncthreads();
    if constexpr (LN) {                      // per-pixel LN over 64 channels
        static_assert(!LN || (CPAD == 64 && PX == 128), "LN path assumes 64ch/128px");
        int p = tid & 127, q = tid >> 7;     // q in {0,1}: 32 channels each
        float s = 0.f, s2 = 0.f;
        #pragma unroll
        for (int c = q * 32; c < q * 32 + 32; ++c) {
            float v = bf2f(sX[p * 64 + ((((c >> 3) ^ (p & 7)) << 3) | (c & 7))]);
            s += v; s2 += v * v;
        }
        sPa[tid] = s; sPb[tid] = s2;
        __syncthreads();
        if (tid < 128) {
            float ss = sPa[tid] + sPa[tid+128];
            float qq = sPb[tid] + sPb[tid+128];
            float mu = ss * (1.f/64.f);
            float var = qq * (1.f/64.f) - mu * mu;
            sMu[tid] = mu; sInv[tid] = rsqrtf(var + 1e-5f);
        }
        __syncthreads();
        float mu = sMu[p], inv = sInv[p];
        #pragma unroll
        for (int c = q * 32; c < q * 32 + 32; ++c) {
            int sw = p * 64 + ((((c >> 3) ^ (p & 7)) << 3) | (c & 7));
            float v = bf2f(sX[sw]);
            sX[sw] = f2bf((v - mu) * inv * lnw[c] + lnb[c]);
        }
        __syncthreads();
    }

    int pxl = lane & 15, quad = lane >> 4;
    for (int o0 = 0; o0 < COUT; o0 += 64) {  // ---- barrier-free compute ----
        f32x4 acc[NPT][4];
        #pragma unroll
        for (int pt = 0; pt < NPT; ++pt)
            #pragma unroll
            for (int ot = 0; ot < 4; ++ot) acc[pt][ot] = (f32x4){0.f, 0.f, 0.f, 0.f};
        #pragma unroll
        for (int s = 0; s < NSL; ++s) {
            int kb = s * 4 + quad;
            bf16x8 bfr[NPT];
            #pragma unroll
            for (int pt = 0; pt < NPT; ++pt) {
                int p = pt * 64 + wave * 16 + pxl;
                bfr[pt] = *(const bf16x8*)&sX[p * CPAD + ((kb ^ (p & 7)) << 3)];
            }
            #pragma unroll
            for (int ot = 0; ot < 4; ++ot) {
                int o = o0 + ot * 16 + pxl;
                bf16x8 afr = *(const bf16x8*)&sW[o * CPAD + ((kb ^ (o & 7)) << 3)];
                #pragma unroll
                for (int pt = 0; pt < NPT; ++pt)
                    acc[pt][ot] = __builtin_amdgcn_mfma_f32_16x16x32_bf16(afr, bfr[pt], acc[pt][ot], 0, 0, 0);
            }
        }
        #pragma unroll
        for (int pt = 0; pt < NPT; ++pt) {
            int pgl = hw0 + pt * 64 + wave * 16 + pxl;
            #pragma unroll
            for (int ot = 0; ot < 4; ++ot) {
                #pragma unroll
                for (int r = 0; r < 4; ++r) {
                    int og = o0 + ot * 16 + quad * 4 + r;
                    if (COUT % 64 == 0 || og < COUT) {
                        size_t ob = (size_t)og * P_ + pgl;
                        float v = acc[pt][ot][r] + bias[og];
                        if constexpr (RES) v += res[ob];
                        out[ob] = v;
                    }
                }
            }
        }
    }
}

// ========= MFMA 128x128x256 GEMM core (attn logits / AV products) ==========
// Same fragment/swizzle conventions as conv_mfma_kernel (proven layout):
// sA[m][k], sB[n][k], both 128 rows x 256 k bf16, XOR-swizzled 16B k-blocks.
// 4 waves; wave owns rows [wave*32, wave*32+32) x all 128 cols.
// acc[mt][jt]: D row = wave*32+mt*16+quad*4+r, col = jt*16+pxl.
__device__ __forceinline__ void mfma_core_256(const unsigned short* sA,
        const unsigned short* sB, int wave, int lane, f32x4 acc[2][8]) {
    int pxl = lane & 15, quad = lane >> 4;
    #pragma unroll
    for (int mt = 0; mt < 2; ++mt)
        #pragma unroll
        for (int jt = 0; jt < 8; ++jt) acc[mt][jt] = (f32x4){0.f, 0.f, 0.f, 0.f};
    #pragma unroll
    for (int s = 0; s < 8; ++s) {
        int kb = s * 4 + quad;
        bf16x8 af[2];
        #pragma unroll
        for (int mt = 0; mt < 2; ++mt) {
            int im = wave * 32 + mt * 16 + pxl;
            af[mt] = *(const bf16x8*)&sA[im * 256 + ((kb ^ (im & 7)) << 3)];
        }
        #pragma unroll
        for (int jt = 0; jt < 8; ++jt) {
            int jn = jt * 16 + pxl;
            bf16x8 bf = *(const bf16x8*)&sB[jn * 256 + ((kb ^ (jn & 7)) << 3)];
            #pragma unroll
            for (int mt = 0; mt < 2; ++mt)
                acc[mt][jt] = __builtin_amdgcn_mfma_f32_16x16x32_bf16(af[mt], bf, acc[mt][jt], 0, 0, 0);
        }
    }
}

// stage 128 rows x 256 k from global [row][k] (k contiguous): float4 loads,
// packed bf16x4 LDS writes into swizzled [row][k].
#define STAGE_DIRECT(sDst, ROWADDR)                                          \
    {   uint32_t* s32_ = (uint32_t*)(sDst);                                  \
        _Pragma("unroll")                                                    \
        for (int it_ = 0; it_ < 32; ++it_) {                                 \
            int idx_ = tid + it_ * 256;                                      \
            int il_ = idx_ >> 6, r_ = (idx_ & 63) * 4;                       \
            float4 v_ = *(const float4*)(ROWADDR(il_) + r_);                 \
            uint32_t p0_ = (uint32_t)f2bf(v_.x) | ((uint32_t)f2bf(v_.y) << 16); \
            uint32_t p1_ = (uint32_t)f2bf(v_.z) | ((uint32_t)f2bf(v_.w) << 16); \
            int off_ = il_ * 256 + ((((r_ >> 3) ^ (il_ & 7)) << 3) | (r_ & 7)); \
            s32_[off_ >> 1] = p0_;                                           \
            s32_[(off_ >> 1) + 1] = p1_;                                     \
        }                                                                    \
    }

// stage 128 rows x 256 k from global [k][row] (row contiguous): float4 loads
// along row dim, scattered ushort LDS writes (transpose into [row][k]).
#define STAGE_TRANS(sDst, KROWADDR)                                          \
    {   _Pragma("unroll")                                                    \
        for (int it_ = 0; it_ < 32; ++it_) {                                 \
            int idx_ = tid + it_ * 256;                                      \
            int il4_ = (idx_ & 31) * 4, r_ = idx_ >> 5;                      \
            float4 v_ = *(const float4*)(KROWADDR(r_) + il4_);               \
            float vv_[4] = {v_.x, v_.y, v_.z, v_.w};                         \
            int kb_ = r_ >> 3;                                               \
            _Pragma("unroll")                                                \
            for (int e_ = 0; e_ < 4; ++e_) {                                 \
                int il_ = il4_ + e_;                                         \
                (sDst)[il_ * 256 + (((kb_ ^ (il_ & 7)) << 3) | (r_ & 7))] = f2bf(vv_[e_]); \
            }                                                                \
        }                                                                    \
    }

// ---- attention logits partials: part[ks][i][j], K-dim = h (wxw) / w (hxh) --
// wxw (HXH=0): S[i=w][j=u] = sum_r q[ks,r,i] k[ks,r,j]  (global [k][row])
// hxh (HXH=1): S[i=h][j=g] = sum_r q[ks,i,r] k[ks,j,r]  (global [row][k])
template<bool HXH>
__global__ __launch_bounds__(256) void attn_logits_mfma(const float* __restrict__ dw,
        float* __restrict__ part) {
    __shared__ unsigned short sA[128 * 256];
    __shared__ unsigned short sB[128 * 256];
    int tid = threadIdx.x, lane = tid & 63, wave = tid >> 6;
    int i0 = (blockIdx.x & 1) * 128, j0 = (blockIdx.x >> 1) * 128;
    int ks = blockIdx.y;
    const float* qc = dw + ((size_t)ks << 16);
    const float* kc = dw + ((size_t)(64 + ks) << 16);
    if constexpr (HXH) {
        #define ROWA_Q(il) (qc + (size_t)(i0 + (il)) * 256)
        #define ROWA_K(il) (kc + (size_t)(j0 + (il)) * 256)
        STAGE_DIRECT(sA, ROWA_Q)
        STAGE_DIRECT(sB, ROWA_K)
        #undef ROWA_Q
        #undef ROWA_K
    } else {
        #define KROW_Q(r) (qc + (size_t)(r) * 256 + i0)
        #define KROW_K(r) (kc + (size_t)(r) * 256 + j0)
        STAGE_TRANS(sA, KROW_Q)
        STAGE_TRANS(sB, KROW_K)
        #undef KROW_Q
        #undef KROW_K
    }
    __syncthreads();
    f32x4 acc[2][8];
    mfma_core_256(sA, sB, wave, lane, acc);
    int pxl = lane & 15, quad = lane >> 4;
    float* pb = part + ((size_t)ks << 16);
    #pragma unroll
    for (int mt = 0; mt < 2; ++mt) {
        #pragma unroll
        for (int jt = 0; jt < 8; ++jt) {
            #pragma unroll
            for (int r = 0; r < 4; ++r) {
                int i = i0 + wave * 32 + mt * 16 + quad * 4 + r;
                int j = j0 + jt * 16 + pxl;
                pb[(size_t)i * 256 + j] = acc[mt][jt][r];
            }
        }
    }
}

// ---- av_w: Out[m=(h,c)][u] = sum_w V[c,h,w] * Att[w,u] ---------------------
__global__ __launch_bounds__(256) void av_w_mfma(const float* __restrict__ dw,
        const float* __restrict__ att, float* __restrict__ out) {
    __shared__ unsigned short sA[128 * 256];
    __shared__ unsigned short sB[128 * 256];
    int tid = threadIdx.x, lane = tid & 63, wave = tid >> 6;
    int m0 = blockIdx.x * 128, u0 = blockIdx.y * 128;
    #define ROWA_V(il) (dw + ((size_t)(128 + ((m0 + (il)) & 63)) << 16) \
                           + ((m0 + (il)) >> 6) * 256)
    #define KROW_ATT(r) (att + (size_t)(r) * 256 + u0)
    STAGE_DIRECT(sA, ROWA_V)
    STAGE_TRANS(sB, KROW_ATT)
    #undef ROWA_V
    #undef KROW_ATT
    __syncthreads();
    f32x4 acc[2][8];
    mfma_core_256(sA, sB, wave, lane, acc);
    int pxl = lane & 15, quad = lane >> 4;
    #pragma unroll
    for (int mt = 0; mt < 2; ++mt) {
        #pragma unroll
        for (int jt = 0; jt < 8; ++jt) {
            #pragma unroll
            for (int r = 0; r < 4; ++r) {
                int m = m0 + wave * 32 + mt * 16 + quad * 4 + r;
                int c = m & 63, h = m >> 6;
                out[((size_t)c << 16) + h * 256 + u0 + jt * 16 + pxl] = acc[mt][jt][r];
            }
        }
    }
}

// ---- av_h: Out[c][h][w] = sum_g Att[h,g] * V[c,g,w] ------------------------
__global__ __launch_bounds__(256) void av_h_mfma(const float* __restrict__ dw,
        const float* __restrict__ att, float* __restrict__ out) {
    __shared__ unsigned short sA[128 * 256];
    __shared__ unsigned short sB[128 * 256];
    int tid = threadIdx.x, lane = tid & 63, wave = tid >> 6;
    int c = blockIdx.x >> 1;
    int w0 = (blockIdx.x & 1) * 128;
    int h0 = blockIdx.y * 128;
    const float* vc = dw + ((size_t)(128 + c) << 16);
    #define ROWA_ATT(il) (att + (size_t)(h0 + (il)) * 256)
    #define KROW_V(r) (vc + (size_t)(r) * 256 + w0)
    STAGE_DIRECT(sA, ROWA_ATT)
    STAGE_TRANS(sB, KROW_V)
    #undef ROWA_ATT
    #undef KROW_V
    __syncthreads();
    f32x4 acc[2][8];
    mfma_core_256(sA, sB, wave, lane, acc);
    int pxl = lane & 15, quad = lane >> 4;
    #pragma unroll
    for (int mt = 0; mt < 2; ++mt) {
        #pragma unroll
        for (int jt = 0; jt < 8; ++jt) {
            #pragma unroll
            for (int r = 0; r < 4; ++r) {
                int h = h0 + wave * 32 + mt * 16 + quad * 4 + r;
                out[((size_t)c << 16) + h * 256 + w0 + jt * 16 + pxl] = acc[mt][jt][r];
            }
        }
    }
}

// ---------------- sum 64 K-split partials, scale by temp, softmax row -------
__global__ __launch_bounds__(256) void softmax_kernel(const float* __restrict__ part,
        const float* __restrict__ temp, float* __restrict__ att) {
    int i = blockIdx.x;
    int j = threadIdx.x;
    size_t rowoff = (size_t)i * 256 + j;
    float s = 0.f;
    #pragma unroll
    for (int kk = 0; kk < 64; ++kk) s += part[(size_t)kk * 65536 + rowoff];
    s *= temp[0];
    __shared__ float redA[4], redB[4];
    int wv = j >> 6, ln = j & 63;
    float m = s;
    #pragma unroll
    for (int off = 32; off; off >>= 1) m = fmaxf(m, __shfl_down(m, off, 64));
    if (ln == 0) redA[wv] = m;
    __syncthreads();
    m = fmaxf(fmaxf(redA[0], redA[1]), fmaxf(redA[2], redA[3]));
    float e = expf(s - m);
    float t2 = e;
    #pragma unroll
    for (int off = 32; off; off >>= 1) t2 += __shfl_down(t2, off, 64);
    if (ln == 0) redB[wv] = t2;
    __syncthreads();
    float tot = redB[0] + redB[1] + redB[2] + redB[3];
    att[rowoff] = e / tot;
}

// ======= wave-per-row depthwise 3x3 + bias, optional L2-norm over w =========
template<bool NORM>
__global__ __launch_bounds__(256) void dw_row_kernel(const float* __restrict__ in,
        const float* __restrict__ w9, const float* __restrict__ bias,
        float* __restrict__ out) {
    int row = __builtin_amdgcn_readfirstlane(blockIdx.x * 4 + (threadIdx.x >> 6));
    int o = row >> 8, h = row & 255;
    int lane = threadIdx.x & 63;
    const float* ip = in + ((size_t)o << 16);
    const float* wp = w9 + o * 9;
    float b = bias[o];
    float4 acc = make_float4(b, b, b, b);
    #pragma unroll
    for (int dy = -1; dy <= 1; ++dy) {
        int hh = h + dy;
        float4 v = make_float4(0.f, 0.f, 0.f, 0.f);
        if (hh >= 0 && hh <= 255)
            v = *(const float4*)(ip + hh * 256 + lane * 4);
        float lft = __shfl(v.w, lane - 1);
        float rgt = __shfl(v.x, lane + 1);
        if (lane == 0)  lft = 0.f;
        if (lane == 63) rgt = 0.f;
        float w0 = wp[(dy+1)*3], w1 = wp[(dy+1)*3+1], w2 = wp[(dy+1)*3+2];
        acc.x += w0*lft + w1*v.x + w2*v.y;
        acc.y += w0*v.x + w1*v.y + w2*v.z;
        acc.z += w0*v.y + w1*v.z + w2*v.w;
        acc.w += w0*v.z + w1*v.w + w2*rgt;
    }
    if constexpr (NORM) {
        if (o < 128) {   // q,k channels: l2-normalize this w-row
            float s = acc.x*acc.x + acc.y*acc.y + acc.z*acc.z + acc.w*acc.w;
            #pragma unroll
            for (int off = 32; off; off >>= 1) s += __shfl_xor(s, off, 64);
            float inv = 1.0f / fmaxf(sqrtf(s), 1e-12f);
            acc.x *= inv; acc.y *= inv; acc.z *= inv; acc.w *= inv;
        }
    }
    *(float4*)(out + ((size_t)o << 16) + h * 256 + lane * 4) = acc;
}

// ===== wave-per-row FFN depthwise 3x3 pair fused with exact-GELU gate =======
__global__ __launch_bounds__(256) void ffn_dw_row_kernel(const float* __restrict__ hid,
        const float* __restrict__ w9, const float* __restrict__ bias,
        float* __restrict__ g) {
    int row = __builtin_amdgcn_readfirstlane(blockIdx.x * 4 + (threadIdx.x >> 6));
    int i = row >> 8, h = row & 255;
    int lane = threadIdx.x & 63;
    const float* ip1 = hid + ((size_t)i << 16);
    const float* ip2 = ip1 + ((size_t)170 << 16);
    const float* wp1 = w9 + i * 9;
    const float* wp2 = w9 + (i + 170) * 9;
    float ba = bias[i], bb = bias[i + 170];
    float4 a = make_float4(ba, ba, ba, ba);
    float4 c = make_float4(bb, bb, bb, bb);
    #pragma unroll
    for (int dy = -1; dy <= 1; ++dy) {
        int hh = h + dy;
        float4 v1 = make_float4(0.f, 0.f, 0.f, 0.f);
        float4 v2 = make_float4(0.f, 0.f, 0.f, 0.f);
        if (hh >= 0 && hh <= 255) {
            v1 = *(const float4*)(ip1 + hh * 256 + lane * 4);
            v2 = *(const float4*)(ip2 + hh * 256 + lane * 4);
        }
        float l1 = __shfl(v1.w, lane - 1), r1 = __shfl(v1.x, lane + 1);
        float l2 = __shfl(v2.w, lane - 1), r2 = __shfl(v2.x, lane + 1);
        if (lane == 0)  { l1 = 0.f; l2 = 0.f; }
        if (lane == 63) { r1 = 0.f; r2 = 0.f; }
        float u0 = wp1[(dy+1)*3], u1 = wp1[(dy+1)*3+1], u2 = wp1[(dy+1)*3+2];
        float q0 = wp2[(dy+1)*3], q1 = wp2[(dy+1)*3+1], q2 = wp2[(dy+1)*3+2];
        a.x += u0*l1   + u1*v1.x + u2*v1.y;
        a.y += u0*v1.x + u1*v1.y + u2*v1.z;
        a.z += u0*v1.y + u1*v1.z + u2*v1.w;
        a.w += u0*v1.z + u1*v1.w + u2*r1;
        c.x += q0*l2   + q1*v2.x + q2*v2.y;
        c.y += q0*v2.x + q1*v2.y + q2*v2.z;
        c.z += q0*v2.y + q1*v2.z + q2*v2.w;
        c.w += q0*v2.z + q1*v2.w + q2*r2;
    }
    const float ISQ2 = 0.70710678118654752440f;
    float4 r;
    r.x = 0.5f * a.x * (1.0f + erff(a.x * ISQ2)) * c.x;
    r.y = 0.5f * a.y * (1.0f + erff(a.y * ISQ2)) * c.y;
    r.z = 0.5f * a.z * (1.0f + erff(a.z * ISQ2)) * c.z;
    r.w = 0.5f * a.w * (1.0f + erff(a.w * ISQ2)) * c.w;
    *(float4*)(g + ((size_t)i << 16) + h * 256 + lane * 4) = r;
}

// ---------------- l2 normalize over (c,w), per (q|k, h) ---------------------
__global__ __launch_bounds__(256) void l2norm_h_kernel(float* __restrict__ dw) {
    int h = blockIdx.x, qk = blockIdx.y;
    float* base = dw + ((size_t)(qk*64) << 16) + h*256;
    int tid = threadIdx.x;
    float s = 0.f;
    for (int idx = tid; idx < 16384; idx += 256) {
        int c = idx >> 8, w = idx & 255;
        float v = base[((size_t)c << 16) + w];
        s += v * v;
    }
    #pragma unroll
    for (int off = 32; off; off >>= 1) s += __shfl_down(s, off, 64);
    __shared__ float red[4];
    int wv = tid >> 6, ln = tid & 63;
    if (ln == 0) red[wv] = s;
    __syncthreads();
    float tot = red[0] + red[1] + red[2] + red[3];
    float inv = 1.0f / fmaxf(sqrtf(tot), 1e-12f);
    for (int idx = tid; idx < 16384; idx += 256) {
        int c = idx >> 8, w = idx & 255;
        base[((size_t)c << 16) + w] *= inv;
    }
}

// ---------------------------------------------------------------------------
extern "C" void kernel_launch(void* const* d_in, const int* in_sizes, int n_in,
                              void* d_out, int out_size, void* d_ws, size_t ws_size,
                              hipStream_t stream) {
    (void)in_sizes; (void)n_in; (void)out_size; (void)ws_size;
    const float* x = (const float*)d_in[0];
    float* ws  = (float*)d_ws;
    float* out = (float*)d_out;
    float* DW   = ws + DW_OFF;
    float* QKV  = ws + QKV_OFF;
    float* ATTP = ws + ATTP_OFF;   // aliases QKV (dead by the time it's used)
    float* Y    = ws + Y_OFF;
    float* ATT  = ws + ATT_OFF;
    float* HID  = ws + HID_OFF;
    float* G    = ws + G_OFF;

    for (int b = 0; b < 4; ++b) {
        const float* xb = x + (size_t)b * 64 * P_;
        float* outb = out + (size_t)b * 64 * P_;

        // ===== stage A: attention over W (wxw); m -> d_out =====
        conv_mfma_kernel<64,64,192,192,128,true,false><<<512, 256, 0, stream>>>(xb,
                (const float*)d_in[2], (const float*)d_in[3],
                (const float*)d_in[4], (const float*)d_in[5], QKV, nullptr);
        dw_row_kernel<true><<<12288, 256, 0, stream>>>(QKV,
                (const float*)d_in[6], (const float*)d_in[7], DW);
        attn_logits_mfma<false><<<dim3(4,64), 256, 0, stream>>>(DW, ATTP);
        softmax_kernel<<<256, 256, 0, stream>>>(ATTP, (const float*)d_in[10], ATT);
        av_w_mfma<<<dim3(128,2), 256, 0, stream>>>(DW, ATT, Y);
        conv_mfma_kernel<64,64,64,64,128,false,true><<<512, 256, 0, stream>>>(Y,
                nullptr, nullptr,
                (const float*)d_in[8], (const float*)d_in[9], outb, xb);

        // ===== stage B: attention over H (hxh); z -> d_out =====
        conv_mfma_kernel<64,64,192,192,128,true,false><<<512, 256, 0, stream>>>(outb,
                (const float*)d_in[11], (const float*)d_in[12],
                (const float*)d_in[13], (const float*)d_in[14], QKV, nullptr);
        dw_row_kernel<false><<<12288, 256, 0, stream>>>(QKV,
                (const float*)d_in[15], (const float*)d_in[16], DW);
        l2norm_h_kernel<<<dim3(256,2), 256, 0, stream>>>(DW);
        attn_logits_mfma<true><<<dim3(4,64), 256, 0, stream>>>(DW, ATTP);
        softmax_kernel<<<256, 256, 0, stream>>>(ATTP, (const float*)d_in[19], ATT);
        av_h_mfma<<<dim3(128,2), 256, 0, stream>>>(DW, ATT, Y);
        conv_mfma_kernel<64,64,64,64,128,false,true><<<512, 256, 0, stream>>>(Y,
                nullptr, nullptr,
                (const float*)d_in[17], (const float*)d_in[18], outb, outb);

        // ===== stage C: gated FFN; z + ffn -> d_out =====
        conv_mfma_kernel<64,64,340,384,128,true,false><<<512, 256, 0, stream>>>(outb,
                (const float*)d_in[20], (const float*)d_in[21],
                (const float*)d_in[22], (const float*)d_in[23], HID, nullptr);
        ffn_dw_row_kernel<<<10880, 256, 0, stream>>>(HID, (const float*)d_in[24],
                (const float*)d_in[25], G);
        conv_mfma_kernel<170,192,64,64,128,false,true><<<512, 256, 0, stream>>>(G,
                nullptr, nullptr,
                (const float*)d_in[26], (const float*)d_in[27], outb, outb);
    }
}

// Round 4
// 1697.663 us; speedup vs baseline: 1.0806x; 1.0806x over previous
//
#include <hip/hip_runtime.h>
#include <math.h>
#include <stdint.h>

// Problem constants (per batch): C=64, H=W=256, P=65536 pixels.
#define P_ 65536

// ---- per-batch workspace layout (float offsets). Peak = 33,423,360 floats
#define DW_OFF   0ul            // 192*P (q,k,v post-dwconv)
#define QKV_OFF  12582912ul     // 192*P (pre-dwconv)  [dead after dwconv]
#define ATTP_OFF QKV_OFF        // 64*P K-split partials ALIAS dead QKV region
#define Y_OFF    25165824ul     // 64*P  (attn out)
#define ATT_OFF  31457280ul     // P     (softmaxed attention)
// stage C overlays:
#define HID_OFF  0ul            // 340*P
#define G_OFF    22282240ul     // 170*P

typedef __attribute__((ext_vector_type(8))) short bf16x8;   // 8 bf16 in 4 VGPRs
typedef __attribute__((ext_vector_type(4))) float f32x4;

__device__ __forceinline__ unsigned short f2bf(float f) {   // RNE fp32->bf16
    uint32_t u = __float_as_uint(f);
    return (unsigned short)((u + 0x7FFFu + ((u >> 16) & 1u)) >> 16);
}
__device__ __forceinline__ float bf2f(unsigned short h) {
    return __uint_as_float((uint32_t)h << 16);
}

// ============== MFMA 1x1 conv: out[o,p] = sum_c W[o,c]*X[c,p] ===============
// PX-pixel tile per block, 256 threads = 4 waves. Weight slab of COPAD
// outputs (<=192) staged once; COUT>COPAD split across gridDim.y (obase).
// X tile staged once (+ optional LN). o-chunk compute loop is barrier-free.
// A-frag: A[m=lane&15][k=quad*8+j]; B-frag: B[k=quad*8+j][n=lane&15];
// D: row=(quad*4+reg) (o), col=lane&15 (px). fp32 epilogue: +bias [+res].
template<int CIN, int CPAD, int COUT, int COPAD, int PX, bool LN, bool RES>
__global__ __launch_bounds__(256) void conv_mfma_kernel(
        const float* __restrict__ in, const float* __restrict__ lnw,
        const float* __restrict__ lnb, const float* __restrict__ Wt,
        const float* __restrict__ bias, float* __restrict__ out,
        const float* __restrict__ res) {
    constexpr int NSL = CPAD / 32;           // K slices of 32
    constexpr int NPT = PX / 64;             // px sub-tiles per wave
    __shared__ unsigned short sX[PX * CPAD];
    __shared__ unsigned short sW[COPAD * CPAD];
    __shared__ float sPa[256], sPb[256], sMu[128], sInv[128];
    int tid = threadIdx.x;
    int hw0 = blockIdx.x * PX;
    int obase = blockIdx.y * COPAD;
    int lane = tid & 63, wave = tid >> 6;

    {   // ---- stage X: fp32 global -> bf16 swizzled LDS [px][c] ----
        uint32_t* sX32 = (uint32_t*)sX;
        #pragma unroll
        for (int it = 0; it < PX * CPAD / 512; ++it) {
            int idx = tid + it * 256;
            int p = idx & (PX - 1), c = (idx / PX) * 2;
            float v0 = (c < CIN)     ? in[(size_t)c * P_ + hw0 + p]     : 0.f;
            float v1 = (c + 1 < CIN) ? in[(size_t)(c+1) * P_ + hw0 + p] : 0.f;
            uint32_t pk = (uint32_t)f2bf(v0) | ((uint32_t)f2bf(v1) << 16);
            int kb = c >> 3;
            sX32[(p * CPAD + (((kb ^ (p & 7)) << 3) | (c & 7))) >> 1] = pk;
        }
    }
    {   // ---- stage weight slab [obase, obase+COPAD): [o][c] bf16 swizzled --
        uint32_t* sW32 = (uint32_t*)sW;
        #pragma unroll
        for (int it = 0; it < COPAD * CPAD / 512; ++it) {
            int idx = tid + it * 256;
            int c2 = idx % (CPAD / 2), o = idx / (CPAD / 2);
            int c = c2 * 2, og = obase + o;
            float v0 = (og < COUT && c < CIN)     ? Wt[(size_t)og * CIN + c]     : 0.f;
            float v1 = (og < COUT && c + 1 < CIN) ? Wt[(size_t)og * CIN + c + 1] : 0.f;
            uint32_t pk = (uint32_t)f2bf(v0) | ((uint32_t)f2bf(v1) << 16);
            int kb = c >> 3;
            sW32[(o * CPAD + (((kb ^ (o & 7)) << 3) | (c & 7))) >> 1] = pk;
        }
    }
    __syncthreads();
    if constexpr (LN) {                      // per-pixel LN over 64 channels
        static_assert(!LN || (CPAD == 64 && PX == 128), "LN path assumes 64ch/128px");
        int p = tid & 127, q = tid >> 7;     // q in {0,1}: 32 channels each
        float s = 0.f, s2 = 0.f;
        #pragma unroll
        for (int c = q * 32; c < q * 32 + 32; ++c) {
            float v = bf2f(sX[p * 64 + ((((c >> 3) ^ (p & 7)) << 3) | (c & 7))]);
            s += v; s2 += v * v;
        }
        sPa[tid] = s; sPb[tid] = s2;
        __syncthreads();
        if (tid < 128) {
            float ss = sPa[tid] + sPa[tid+128];
            float qq = sPb[tid] + sPb[tid+128];
            float mu = ss * (1.f/64.f);
            float var = qq * (1.f/64.f) - mu * mu;
            sMu[tid] = mu; sInv[tid] = rsqrtf(var + 1e-5f);
        }
        __syncthreads();
        float mu = sMu[p], inv = sInv[p];
        #pragma unroll
        for (int c = q * 32; c < q * 32 + 32; ++c) {
            int sw = p * 64 + ((((c >> 3) ^ (p & 7)) << 3) | (c & 7));
            float v = bf2f(sX[sw]);
            sX[sw] = f2bf((v - mu) * inv * lnw[c] + lnb[c]);
        }
        __syncthreads();
    }

    int pxl = lane & 15, quad = lane >> 4;
    int olim = (COUT - obase < COPAD) ? (COUT - obase) : COPAD;
    for (int o0 = 0; o0 < olim; o0 += 64) {  // ---- barrier-free compute ----
        f32x4 acc[NPT][4];
        #pragma unroll
        for (int pt = 0; pt < NPT; ++pt)
            #pragma unroll
            for (int ot = 0; ot < 4; ++ot) acc[pt][ot] = (f32x4){0.f, 0.f, 0.f, 0.f};
        #pragma unroll
        for (int s = 0; s < NSL; ++s) {
            int kb = s * 4 + quad;
            bf16x8 bfr[NPT];
            #pragma unroll
            for (int pt = 0; pt < NPT; ++pt) {
                int p = pt * 64 + wave * 16 + pxl;
                bfr[pt] = *(const bf16x8*)&sX[p * CPAD + ((kb ^ (p & 7)) << 3)];
            }
            #pragma unroll
            for (int ot = 0; ot < 4; ++ot) {
                int o = o0 + ot * 16 + pxl;
                bf16x8 afr = *(const bf16x8*)&sW[o * CPAD + ((kb ^ (o & 7)) << 3)];
                #pragma unroll
                for (int pt = 0; pt < NPT; ++pt)
                    acc[pt][ot] = __builtin_amdgcn_mfma_f32_16x16x32_bf16(afr, bfr[pt], acc[pt][ot], 0, 0, 0);
            }
        }
        #pragma unroll
        for (int pt = 0; pt < NPT; ++pt) {
            int pgl = hw0 + pt * 64 + wave * 16 + pxl;
            #pragma unroll
            for (int ot = 0; ot < 4; ++ot) {
                #pragma unroll
                for (int r = 0; r < 4; ++r) {
                    int og = obase + o0 + ot * 16 + quad * 4 + r;
                    if ((COUT % 64 == 0 && COUT <= COPAD) || og < COUT) {
                        size_t ob = (size_t)og * P_ + pgl;
                        float v = acc[pt][ot][r] + bias[og];
                        if constexpr (RES) v += res[ob];
                        out[ob] = v;
                    }
                }
            }
        }
    }
}

// ========= MFMA 128x128x256 GEMM core (attn logits / AV products) ==========
// K processed in 4 sequential 64-steps; per step stage 128x64 bf16 A and B
// (32 KB LDS total -> 4-5 blocks/CU). Same fragment/swizzle as conv kernel,
// row stride 64. 4 waves; wave owns rows [wave*32, wave*32+32).
// acc[mt][jt]: D row = wave*32+mt*16+quad*4+r, col = jt*16+pxl.
__device__ __forceinline__ void mfma_step64(const unsigned short* sA,
        const unsigned short* sB, int wave, int lane, f32x4 acc[2][8]) {
    int pxl = lane & 15, quad = lane >> 4;
    #pragma unroll
    for (int s = 0; s < 2; ++s) {
        int kb = s * 4 + quad;
        bf16x8 af[2];
        #pragma unroll
        for (int mt = 0; mt < 2; ++mt) {
            int im = wave * 32 + mt * 16 + pxl;
            af[mt] = *(const bf16x8*)&sA[im * 64 + ((kb ^ (im & 7)) << 3)];
        }
        #pragma unroll
        for (int jt = 0; jt < 8; ++jt) {
            int jn = jt * 16 + pxl;
            bf16x8 bf = *(const bf16x8*)&sB[jn * 64 + ((kb ^ (jn & 7)) << 3)];
            #pragma unroll
            for (int mt = 0; mt < 2; ++mt)
                acc[mt][jt] = __builtin_amdgcn_mfma_f32_16x16x32_bf16(af[mt], bf, acc[mt][jt], 0, 0, 0);
        }
    }
}

// stage 128 rows x 64 k (k-step Q) from global [row][k] (k contiguous)
#define STAGE_DIRECT64(sDst, ROWADDR, Q)                                     \
    {   uint32_t* s32_ = (uint32_t*)(sDst);                                  \
        _Pragma("unroll")                                                    \
        for (int it_ = 0; it_ < 8; ++it_) {                                  \
            int idx_ = tid + it_ * 256;                                      \
            int il_ = idx_ >> 4, k_ = (idx_ & 15) * 4;                       \
            float4 v_ = *(const float4*)(ROWADDR(il_) + (Q) * 64 + k_);      \
            uint32_t p0_ = (uint32_t)f2bf(v_.x) | ((uint32_t)f2bf(v_.y) << 16); \
            uint32_t p1_ = (uint32_t)f2bf(v_.z) | ((uint32_t)f2bf(v_.w) << 16); \
            int off_ = il_ * 64 + ((((k_ >> 3) ^ (il_ & 7)) << 3) | (k_ & 7)); \
            s32_[off_ >> 1] = p0_;                                           \
            s32_[(off_ >> 1) + 1] = p1_;                                     \
        }                                                                    \
    }

// stage 128 rows x 64 k (k-step Q) from global [k][row] (row contiguous):
// float4 along row dim, scattered ushort LDS writes (transpose).
#define STAGE_TRANS64(sDst, KROWADDR, Q)                                     \
    {   _Pragma("unroll")                                                    \
        for (int it_ = 0; it_ < 8; ++it_) {                                  \
            int idx_ = tid + it_ * 256;                                      \
            int r_ = idx_ >> 5, il4_ = (idx_ & 31) * 4;                      \
            float4 v_ = *(const float4*)(KROWADDR((Q) * 64 + r_) + il4_);    \
            float vv_[4] = {v_.x, v_.y, v_.z, v_.w};                         \
            int kb_ = r_ >> 3;                                               \
            _Pragma("unroll")                                                \
            for (int e_ = 0; e_ < 4; ++e_) {                                 \
                int il_ = il4_ + e_;                                         \
                (sDst)[il_ * 64 + (((kb_ ^ (il_ & 7)) << 3) | (r_ & 7))] = f2bf(vv_[e_]); \
            }                                                                \
        }                                                                    \
    }

// ---- attention logits partials: part[ks][i][j], K-dim = h (wxw) / w (hxh) --
// wxw (HXH=0): S[i=w][j=u] = sum_r q[ks,r,i] k[ks,r,j]  (global [k][row])
// hxh (HXH=1): S[i=h][j=g] = sum_r q[ks,i,r] k[ks,j,r]  (global [row][k])
template<bool HXH>
__global__ __launch_bounds__(256) void attn_logits_mfma(const float* __restrict__ dw,
        float* __restrict__ part) {
    __shared__ unsigned short sA[128 * 64];
    __shared__ unsigned short sB[128 * 64];
    int tid = threadIdx.x, lane = tid & 63, wave = tid >> 6;
    int i0 = (blockIdx.x & 1) * 128, j0 = (blockIdx.x >> 1) * 128;
    int ks = blockIdx.y;
    const float* qc = dw + ((size_t)ks << 16);
    const float* kc = dw + ((size_t)(64 + ks) << 16);
    f32x4 acc[2][8];
    #pragma unroll
    for (int mt = 0; mt < 2; ++mt)
        #pragma unroll
        for (int jt = 0; jt < 8; ++jt) acc[mt][jt] = (f32x4){0.f, 0.f, 0.f, 0.f};
    for (int q = 0; q < 4; ++q) {
        if (q) __syncthreads();              // prior compute reads done
        if constexpr (HXH) {
            #define ROWA_Q(il) (qc + (size_t)(i0 + (il)) * 256)
            #define ROWA_K(il) (kc + (size_t)(j0 + (il)) * 256)
            STAGE_DIRECT64(sA, ROWA_Q, q)
            STAGE_DIRECT64(sB, ROWA_K, q)
            #undef ROWA_Q
            #undef ROWA_K
        } else {
            #define KROW_Q(r) (qc + (size_t)(r) * 256 + i0)
            #define KROW_K(r) (kc + (size_t)(r) * 256 + j0)
            STAGE_TRANS64(sA, KROW_Q, q)
            STAGE_TRANS64(sB, KROW_K, q)
            #undef KROW_Q
            #undef KROW_K
        }
        __syncthreads();
        mfma_step64(sA, sB, wave, lane, acc);
    }
    int pxl = lane & 15, quad = lane >> 4;
    float* pb = part + ((size_t)ks << 16);
    #pragma unroll
    for (int mt = 0; mt < 2; ++mt) {
        #pragma unroll
        for (int jt = 0; jt < 8; ++jt) {
            #pragma unroll
            for (int r = 0; r < 4; ++r) {
                int i = i0 + wave * 32 + mt * 16 + quad * 4 + r;
                int j = j0 + jt * 16 + pxl;
                pb[(size_t)i * 256 + j] = acc[mt][jt][r];
            }
        }
    }
}

// ---- av_w: Out[m=(h,c)][u] = sum_w V[c,h,w] * Att[w,u] ---------------------
__global__ __launch_bounds__(256) void av_w_mfma(const float* __restrict__ dw,
        const float* __restrict__ att, float* __restrict__ out) {
    __shared__ unsigned short sA[128 * 64];
    __shared__ unsigned short sB[128 * 64];
    int tid = threadIdx.x, lane = tid & 63, wave = tid >> 6;
    int m0 = blockIdx.x * 128, u0 = blockIdx.y * 128;
    f32x4 acc[2][8];
    #pragma unroll
    for (int mt = 0; mt < 2; ++mt)
        #pragma unroll
        for (int jt = 0; jt < 8; ++jt) acc[mt][jt] = (f32x4){0.f, 0.f, 0.f, 0.f};
    for (int q = 0; q < 4; ++q) {
        if (q) __syncthreads();
        #define ROWA_V(il) (dw + ((size_t)(128 + ((m0 + (il)) & 63)) << 16) \
                               + ((m0 + (il)) >> 6) * 256)
        #define KROW_ATT(r) (att + (size_t)(r) * 256 + u0)
        STAGE_DIRECT64(sA, ROWA_V, q)
        STAGE_TRANS64(sB, KROW_ATT, q)
        #undef ROWA_V
        #undef KROW_ATT
        __syncthreads();
        mfma_step64(sA, sB, wave, lane, acc);
    }
    int pxl = lane & 15, quad = lane >> 4;
    #pragma unroll
    for (int mt = 0; mt < 2; ++mt) {
        #pragma unroll
        for (int jt = 0; jt < 8; ++jt) {
            #pragma unroll
            for (int r = 0; r < 4; ++r) {
                int m = m0 + wave * 32 + mt * 16 + quad * 4 + r;
                int c = m & 63, h = m >> 6;
                out[((size_t)c << 16) + h * 256 + u0 + jt * 16 + pxl] = acc[mt][jt][r];
            }
        }
    }
}

// ---- av_h: Out[c][h][w] = sum_g Att[h,g] * V[c,g,w] ------------------------
__global__ __launch_bounds__(256) void av_h_mfma(const float* __restrict__ dw,
        const float* __restrict__ att, float* __restrict__ out) {
    __shared__ unsigned short sA[128 * 64];
    __shared__ unsigned short sB[128 * 64];
    int tid = threadIdx.x, lane = tid & 63, wave = tid >> 6;
    int c = blockIdx.x >> 1;
    int w0 = (blockIdx.x & 1) * 128;
    int h0 = blockIdx.y * 128;
    const float* vc = dw + ((size_t)(128 + c) << 16);
    f32x4 acc[2][8];
    #pragma unroll
    for (int mt = 0; mt < 2; ++mt)
        #pragma unroll
        for (int jt = 0; jt < 8; ++jt) acc[mt][jt] = (f32x4){0.f, 0.f, 0.f, 0.f};
    for (int q = 0; q < 4; ++q) {
        if (q) __syncthreads();
        #define ROWA_ATT(il) (att + (size_t)(h0 + (il)) * 256)
        #define KROW_V(r) (vc + (size_t)(r) * 256 + w0)
        STAGE_DIRECT64(sA, ROWA_ATT, q)
        STAGE_TRANS64(sB, KROW_V, q)
        #undef ROWA_ATT
        #undef KROW_V
        __syncthreads();
        mfma_step64(sA, sB, wave, lane, acc);
    }
    int pxl = lane & 15, quad = lane >> 4;
    #pragma unroll
    for (int mt = 0; mt < 2; ++mt) {
        #pragma unroll
        for (int jt = 0; jt < 8; ++jt) {
            #pragma unroll
            for (int r = 0; r < 4; ++r) {
                int h = h0 + wave * 32 + mt * 16 + quad * 4 + r;
                out[((size_t)c << 16) + h * 256 + w0 + jt * 16 + pxl] = acc[mt][jt][r];
            }
        }
    }
}

// ---------------- sum 64 K-split partials, scale by temp, softmax row -------
__global__ __launch_bounds__(256) void softmax_kernel(const float* __restrict__ part,
        const float* __restrict__ temp, float* __restrict__ att) {
    int i = blockIdx.x;
    int j = threadIdx.x;
    size_t rowoff = (size_t)i * 256 + j;
    float s = 0.f;
    #pragma unroll
    for (int kk = 0; kk < 64; ++kk) s += part[(size_t)kk * 65536 + rowoff];
    s *= temp[0];
    __shared__ float redA[4], redB[4];
    int wv = j >> 6, ln = j & 63;
    float m = s;
    #pragma unroll
    for (int off = 32; off; off >>= 1) m = fmaxf(m, __shfl_down(m, off, 64));
    if (ln == 0) redA[wv] = m;
    __syncthreads();
    m = fmaxf(fmaxf(redA[0], redA[1]), fmaxf(redA[2], redA[3]));
    float e = expf(s - m);
    float t2 = e;
    #pragma unroll
    for (int off = 32; off; off >>= 1) t2 += __shfl_down(t2, off, 64);
    if (ln == 0) redB[wv] = t2;
    __syncthreads();
    float tot = redB[0] + redB[1] + redB[2] + redB[3];
    att[rowoff] = e / tot;
}

// ======= wave-per-row depthwise 3x3 + bias, optional L2-norm over w =========
template<bool NORM>
__global__ __launch_bounds__(256) void dw_row_kernel(const float* __restrict__ in,
        const float* __restrict__ w9, const float* __restrict__ bias,
        float* __restrict__ out) {
    int row = __builtin_amdgcn_readfirstlane(blockIdx.x * 4 + (threadIdx.x >> 6));
    int o = row >> 8, h = row & 255;
    int lane = threadIdx.x & 63;
    const float* ip = in + ((size_t)o << 16);
    const float* wp = w9 + o * 9;
    float b = bias[o];
    float4 acc = make_float4(b, b, b, b);
    #pragma unroll
    for (int dy = -1; dy <= 1; ++dy) {
        int hh = h + dy;
        float4 v = make_float4(0.f, 0.f, 0.f, 0.f);
        if (hh >= 0 && hh <= 255)
            v = *(const float4*)(ip + hh * 256 + lane * 4);
        float lft = __shfl(v.w, lane - 1);
        float rgt = __shfl(v.x, lane + 1);
        if (lane == 0)  lft = 0.f;
        if (lane == 63) rgt = 0.f;
        float w0 = wp[(dy+1)*3], w1 = wp[(dy+1)*3+1], w2 = wp[(dy+1)*3+2];
        acc.x += w0*lft + w1*v.x + w2*v.y;
        acc.y += w0*v.x + w1*v.y + w2*v.z;
        acc.z += w0*v.y + w1*v.z + w2*v.w;
        acc.w += w0*v.z + w1*v.w + w2*rgt;
    }
    if constexpr (NORM) {
        if (o < 128) {   // q,k channels: l2-normalize this w-row
            float s = acc.x*acc.x + acc.y*acc.y + acc.z*acc.z + acc.w*acc.w;
            #pragma unroll
            for (int off = 32; off; off >>= 1) s += __shfl_xor(s, off, 64);
            float inv = 1.0f / fmaxf(sqrtf(s), 1e-12f);
            acc.x *= inv; acc.y *= inv; acc.z *= inv; acc.w *= inv;
        }
    }
    *(float4*)(out + ((size_t)o << 16) + h * 256 + lane * 4) = acc;
}

// ===== wave-per-row FFN depthwise 3x3 pair fused with exact-GELU gate =======
__global__ __launch_bounds__(256) void ffn_dw_row_kernel(const float* __restrict__ hid,
        const float* __restrict__ w9, const float* __restrict__ bias,
        float* __restrict__ g) {
    int row = __builtin_amdgcn_readfirstlane(blockIdx.x * 4 + (threadIdx.x >> 6));
    int i = row >> 8, h = row & 255;
    int lane = threadIdx.x & 63;
    const float* ip1 = hid + ((size_t)i << 16);
    const float* ip2 = ip1 + ((size_t)170 << 16);
    const float* wp1 = w9 + i * 9;
    const float* wp2 = w9 + (i + 170) * 9;
    float ba = bias[i], bb = bias[i + 170];
    float4 a = make_float4(ba, ba, ba, ba);
    float4 c = make_float4(bb, bb, bb, bb);
    #pragma unroll
    for (int dy = -1; dy <= 1; ++dy) {
        int hh = h + dy;
        float4 v1 = make_float4(0.f, 0.f, 0.f, 0.f);
        float4 v2 = make_float4(0.f, 0.f, 0.f, 0.f);
        if (hh >= 0 && hh <= 255) {
            v1 = *(const float4*)(ip1 + hh * 256 + lane * 4);
            v2 = *(const float4*)(ip2 + hh * 256 + lane * 4);
        }
        float l1 = __shfl(v1.w, lane - 1), r1 = __shfl(v1.x, lane + 1);
        float l2 = __shfl(v2.w, lane - 1), r2 = __shfl(v2.x, lane + 1);
        if (lane == 0)  { l1 = 0.f; l2 = 0.f; }
        if (lane == 63) { r1 = 0.f; r2 = 0.f; }
        float u0 = wp1[(dy+1)*3], u1 = wp1[(dy+1)*3+1], u2 = wp1[(dy+1)*3+2];
        float q0 = wp2[(dy+1)*3], q1 = wp2[(dy+1)*3+1], q2 = wp2[(dy+1)*3+2];
        a.x += u0*l1   + u1*v1.x + u2*v1.y;
        a.y += u0*v1.x + u1*v1.y + u2*v1.z;
        a.z += u0*v1.y + u1*v1.z + u2*v1.w;
        a.w += u0*v1.z + u1*v1.w + u2*r1;
        c.x += q0*l2   + q1*v2.x + q2*v2.y;
        c.y += q0*v2.x + q1*v2.y + q2*v2.z;
        c.z += q0*v2.y + q1*v2.z + q2*v2.w;
        c.w += q0*v2.z + q1*v2.w + q2*r2;
    }
    const float ISQ2 = 0.70710678118654752440f;
    float4 r;
    r.x = 0.5f * a.x * (1.0f + erff(a.x * ISQ2)) * c.x;
    r.y = 0.5f * a.y * (1.0f + erff(a.y * ISQ2)) * c.y;
    r.z = 0.5f * a.z * (1.0f + erff(a.z * ISQ2)) * c.z;
    r.w = 0.5f * a.w * (1.0f + erff(a.w * ISQ2)) * c.w;
    *(float4*)(g + ((size_t)i << 16) + h * 256 + lane * 4) = r;
}

// ---------------- l2 normalize over (c,w), per (q|k, h) ---------------------
__global__ __launch_bounds__(256) void l2norm_h_kernel(float* __restrict__ dw) {
    int h = blockIdx.x, qk = blockIdx.y;
    float* base = dw + ((size_t)(qk*64) << 16) + h*256;
    int tid = threadIdx.x;
    float s = 0.f;
    for (int idx = tid; idx < 16384; idx += 256) {
        int c = idx >> 8, w = idx & 255;
        float v = base[((size_t)c << 16) + w];
        s += v * v;
    }
    #pragma unroll
    for (int off = 32; off; off >>= 1) s += __shfl_down(s, off, 64);
    __shared__ float red[4];
    int wv = tid >> 6, ln = tid & 63;
    if (ln == 0) red[wv] = s;
    __syncthreads();
    float tot = red[0] + red[1] + red[2] + red[3];
    float inv = 1.0f / fmaxf(sqrtf(tot), 1e-12f);
    for (int idx = tid; idx < 16384; idx += 256) {
        int c = idx >> 8, w = idx & 255;
        base[((size_t)c << 16) + w] *= inv;
    }
}

// ---------------------------------------------------------------------------
extern "C" void kernel_launch(void* const* d_in, const int* in_sizes, int n_in,
                              void* d_out, int out_size, void* d_ws, size_t ws_size,
                              hipStream_t stream) {
    (void)in_sizes; (void)n_in; (void)out_size; (void)ws_size;
    const float* x = (const float*)d_in[0];
    float* ws  = (float*)d_ws;
    float* out = (float*)d_out;
    float* DW   = ws + DW_OFF;
    float* QKV  = ws + QKV_OFF;
    float* ATTP = ws + ATTP_OFF;   // aliases QKV (dead by the time it's used)
    float* Y    = ws + Y_OFF;
    float* ATT  = ws + ATT_OFF;
    float* HID  = ws + HID_OFF;
    float* G    = ws + G_OFF;

    for (int b = 0; b < 4; ++b) {
        const float* xb = x + (size_t)b * 64 * P_;
        float* outb = out + (size_t)b * 64 * P_;

        // ===== stage A: attention over W (wxw); m -> d_out =====
        conv_mfma_kernel<64,64,192,192,128,true,false><<<dim3(512,1), 256, 0, stream>>>(xb,
                (const float*)d_in[2], (const float*)d_in[3],
                (const float*)d_in[4], (const float*)d_in[5], QKV, nullptr);
        dw_row_kernel<true><<<12288, 256, 0, stream>>>(QKV,
                (const float*)d_in[6], (const float*)d_in[7], DW);
        attn_logits_mfma<false><<<dim3(4,64), 256, 0, stream>>>(DW, ATTP);
        softmax_kernel<<<256, 256, 0, stream>>>(ATTP, (const float*)d_in[10], ATT);
        av_w_mfma<<<dim3(128,2), 256, 0, stream>>>(DW, ATT, Y);
        conv_mfma_kernel<64,64,64,64,128,false,true><<<dim3(512,1), 256, 0, stream>>>(Y,
                nullptr, nullptr,
                (const float*)d_in[8], (const float*)d_in[9], outb, xb);

        // ===== stage B: attention over H (hxh); z -> d_out =====
        conv_mfma_kernel<64,64,192,192,128,true,false><<<dim3(512,1), 256, 0, stream>>>(outb,
                (const float*)d_in[11], (const float*)d_in[12],
                (const float*)d_in[13], (const float*)d_in[14], QKV, nullptr);
        dw_row_kernel<false><<<12288, 256, 0, stream>>>(QKV,
                (const float*)d_in[15], (const float*)d_in[16], DW);
        l2norm_h_kernel<<<dim3(256,2), 256, 0, stream>>>(DW);
        attn_logits_mfma<true><<<dim3(4,64), 256, 0, stream>>>(DW, ATTP);
        softmax_kernel<<<256, 256, 0, stream>>>(ATTP, (const float*)d_in[19], ATT);
        av_h_mfma<<<dim3(128,2), 256, 0, stream>>>(DW, ATT, Y);
        conv_mfma_kernel<64,64,64,64,128,false,true><<<dim3(512,1), 256, 0, stream>>>(Y,
                nullptr, nullptr,
                (const float*)d_in[17], (const float*)d_in[18], outb, outb);

        // ===== stage C: gated FFN; z + ffn -> d_out =====
        conv_mfma_kernel<64,64,340,192,128,true,false><<<dim3(512,2), 256, 0, stream>>>(outb,
                (const float*)d_in[20], (const float*)d_in[21],
                (const float*)d_in[22], (const float*)d_in[23], HID, nullptr);
        ffn_dw_row_kernel<<<10880, 256, 0, stream>>>(HID, (const float*)d_in[24],
                (const float*)d_in[25], G);
        conv_mfma_kernel<170,192,64,64,64,false,true><<<dim3(1024,1), 256, 0, stream>>>(G,
                nullptr, nullptr,
                (const float*)d_in[26], (const float*)d_in[27], outb, outb);
    }
}

// Round 5
// 1345.298 us; speedup vs baseline: 1.3636x; 1.2619x over previous
//
#include <hip/hip_runtime.h>
#include <math.h>
#include <stdint.h>

// Problem constants (per batch): C=64, H=W=256, P=65536 pixels.
#define P_ 65536

// ---- per-batch workspace layout (float offsets). Slab = 33,423,360 floats
// ---- = 127.5 MiB. If ws_size holds >=2 slabs, batches run CONCURRENTLY via
// ---- blockIdx.z (per-batch slab offset WSB); else serial fallback.
#define DW_OFF   0ul            // 192*P (q,k,v post-dwconv)
#define QKV_OFF  12582912ul     // 192*P (pre-dwconv)  [dead after dwconv]
#define ATTP_OFF QKV_OFF        // 64*P K-split partials ALIAS dead QKV region
#define Y_OFF    25165824ul     // 64*P  (attn out)
#define ATT_OFF  31457280ul     // P     (softmaxed attention)
// stage C overlays:
#define HID_OFF  0ul            // 340*P
#define G_OFF    22282240ul     // 170*P
#define WSB      33423360ul     // floats per batch slab

typedef __attribute__((ext_vector_type(8))) short bf16x8;   // 8 bf16 in 4 VGPRs
typedef __attribute__((ext_vector_type(4))) float f32x4;

__device__ __forceinline__ unsigned short f2bf(float f) {   // RNE fp32->bf16
    uint32_t u = __float_as_uint(f);
    return (unsigned short)((u + 0x7FFFu + ((u >> 16) & 1u)) >> 16);
}
__device__ __forceinline__ float bf2f(unsigned short h) {
    return __uint_as_float((uint32_t)h << 16);
}

// ============== MFMA 1x1 conv: out[o,p] = sum_c W[o,c]*X[c,p] ===============
// PX-pixel tile per block, 256 threads = 4 waves. Weight slab of COPAD
// outputs staged once; COUT>COPAD split across gridDim.y (obase).
// OPERANDS SWAPPED vs r1-r4: A=X (m=pixel), B=W (n=o). D row = pixel,
// col = o  ->  each lane's 4 acc entries are 4 CONSECUTIVE PIXELS of one
// output row => float4 epilogue stores (24 store instrs vs 96 scalar).
// Wave owns o-tiles {wave, wave+4, ...}; X frags hoisted to regs (CPAD=64).
// Zero barriers after staging(+LN).
template<int CIN, int CPAD, int COUT, int COPAD, int PX, bool LN, bool RES>
__global__ __launch_bounds__(256) void conv_mfma_kernel(
        const float* __restrict__ in_, const float* __restrict__ lnw,
        const float* __restrict__ lnb, const float* __restrict__ Wt,
        const float* __restrict__ bias, float* __restrict__ out_,
        const float* __restrict__ res_, size_t zi, size_t zo, size_t zr) {
    constexpr int NSL = CPAD / 32;           // K slices of 32
    constexpr int NMT = PX / 16;             // pixel m-tiles
    constexpr bool HOIST = (CPAD == 64 && PX == 128);
    const float* in = in_ + (size_t)blockIdx.z * zi;
    float* out = out_ + (size_t)blockIdx.z * zo;
    const float* res = nullptr;
    if constexpr (RES) res = res_ + (size_t)blockIdx.z * zr;
    __shared__ unsigned short sX[PX * CPAD];
    __shared__ unsigned short sW[COPAD * CPAD];
    __shared__ float sPa[256], sPb[256], sMu[128], sInv[128];
    int tid = threadIdx.x;
    int hw0 = blockIdx.x * PX;
    int obase = blockIdx.y * COPAD;
    int lane = tid & 63, wave = tid >> 6;

    {   // ---- stage X: fp32 global -> bf16 swizzled LDS [px][c] ----
        uint32_t* sX32 = (uint32_t*)sX;
        #pragma unroll
        for (int it = 0; it < PX * CPAD / 512; ++it) {
            int idx = tid + it * 256;
            int p = idx & (PX - 1), c = (idx / PX) * 2;
            float v0 = (c < CIN)     ? in[(size_t)c * P_ + hw0 + p]     : 0.f;
            float v1 = (c + 1 < CIN) ? in[(size_t)(c+1) * P_ + hw0 + p] : 0.f;
            uint32_t pk = (uint32_t)f2bf(v0) | ((uint32_t)f2bf(v1) << 16);
            int kb = c >> 3;
            sX32[(p * CPAD + (((kb ^ (p & 7)) << 3) | (c & 7))) >> 1] = pk;
        }
    }
    {   // ---- stage weight slab [obase, obase+COPAD): [o][c] bf16 swizzled --
        uint32_t* sW32 = (uint32_t*)sW;
        #pragma unroll
        for (int it = 0; it < COPAD * CPAD / 512; ++it) {
            int idx = tid + it * 256;
            int c2 = idx % (CPAD / 2), o = idx / (CPAD / 2);
            int c = c2 * 2, og = obase + o;
            float v0 = (og < COUT && c < CIN)     ? Wt[(size_t)og * CIN + c]     : 0.f;
            float v1 = (og < COUT && c + 1 < CIN) ? Wt[(size_t)og * CIN + c + 1] : 0.f;
            uint32_t pk = (uint32_t)f2bf(v0) | ((uint32_t)f2bf(v1) << 16);
            int kb = c >> 3;
            sW32[(o * CPAD + (((kb ^ (o & 7)) << 3) | (c & 7))) >> 1] = pk;
        }
    }
    __syncthreads();
    if constexpr (LN) {                      // per-pixel LN over 64 channels
        static_assert(!LN || (CPAD == 64 && PX == 128), "LN path assumes 64ch/128px");
        int p = tid & 127, q = tid >> 7;     // q in {0,1}: 32 channels each
        float s = 0.f, s2 = 0.f;
        #pragma unroll
        for (int c = q * 32; c < q * 32 + 32; ++c) {
            float v = bf2f(sX[p * 64 + ((((c >> 3) ^ (p & 7)) << 3) | (c & 7))]);
            s += v; s2 += v * v;
        }
        sPa[tid] = s; sPb[tid] = s2;
        __syncthreads();
        if (tid < 128) {
            float ss = sPa[tid] + sPa[tid+128];
            float qq = sPb[tid] + sPb[tid+128];
            float mu = ss * (1.f/64.f);
            float var = qq * (1.f/64.f) - mu * mu;
            sMu[tid] = mu; sInv[tid] = rsqrtf(var + 1e-5f);
        }
        __syncthreads();
        float mu = sMu[p], inv = sInv[p];
        #pragma unroll
        for (int c = q * 32; c < q * 32 + 32; ++c) {
            int sw = p * 64 + ((((c >> 3) ^ (p & 7)) << 3) | (c & 7));
            float v = bf2f(sX[sw]);
            sX[sw] = f2bf((v - mu) * inv * lnw[c] + lnb[c]);
        }
        __syncthreads();
    }

    int pxl = lane & 15, quad = lane >> 4;
    int olim = (COUT - obase < COPAD) ? (COUT - obase) : COPAD;
    int ntile = (olim + 15) >> 4;
    bf16x8 xf[HOIST ? NMT * NSL : 1];        // hoisted X frags (regs)
    if constexpr (HOIST) {
        #pragma unroll
        for (int m = 0; m < NMT; ++m)
            #pragma unroll
            for (int s = 0; s < NSL; ++s) {
                int p = m * 16 + pxl;
                int kb = s * 4 + quad;
                xf[m * NSL + s] = *(const bf16x8*)&sX[p * CPAD + ((kb ^ (p & 7)) << 3)];
            }
    }
    for (int ot = wave; ot < ntile; ot += 4) {
        int on = ot * 16 + pxl;              // lane's o within slab
        int og = obase + on;
        f32x4 acc[NMT];
        #pragma unroll
        for (int m = 0; m < NMT; ++m) acc[m] = (f32x4){0.f, 0.f, 0.f, 0.f};
        #pragma unroll
        for (int s = 0; s < NSL; ++s) {
            int kb = s * 4 + quad;
            bf16x8 wf = *(const bf16x8*)&sW[on * CPAD + ((kb ^ (on & 7)) << 3)];
            #pragma unroll
            for (int m = 0; m < NMT; ++m) {
                bf16x8 af;
                if constexpr (HOIST) af = xf[m * NSL + s];
                else {
                    int p = m * 16 + pxl;
                    af = *(const bf16x8*)&sX[p * CPAD + ((kb ^ (p & 7)) << 3)];
                }
                acc[m] = __builtin_amdgcn_mfma_f32_16x16x32_bf16(af, wf, acc[m], 0, 0, 0);
            }
        }
        bool oval = og < COUT;
        float bv = oval ? bias[og] : 0.f;
        #pragma unroll
        for (int m = 0; m < NMT; ++m) {
            if (oval) {
                size_t ob = (size_t)og * P_ + hw0 + m * 16 + quad * 4;
                float4 v = make_float4(acc[m][0] + bv, acc[m][1] + bv,
                                       acc[m][2] + bv, acc[m][3] + bv);
                if constexpr (RES) {
                    float4 rv = *(const float4*)&res[ob];
                    v.x += rv.x; v.y += rv.y; v.z += rv.z; v.w += rv.w;
                }
                *(float4*)&out[ob] = v;
            }
        }
    }
}

// ========= MFMA 128x128x256 GEMM core (attn logits / AV products) ==========
// K in 4 sequential 64-steps; per step stage 128x64 bf16 A and B (32 KB LDS).
// Same fragment/swizzle as conv kernel, row stride 64. 4 waves; wave owns
// rows [wave*32, wave*32+32). acc[mt][jt]: D row = wave*32+mt*16+quad*4+r,
// col = jt*16+pxl.
__device__ __forceinline__ void mfma_step64(const unsigned short* sA,
        const unsigned short* sB, int wave, int lane, f32x4 acc[2][8]) {
    int pxl = lane & 15, quad = lane >> 4;
    #pragma unroll
    for (int s = 0; s < 2; ++s) {
        int kb = s * 4 + quad;
        bf16x8 af[2];
        #pragma unroll
        for (int mt = 0; mt < 2; ++mt) {
            int im = wave * 32 + mt * 16 + pxl;
            af[mt] = *(const bf16x8*)&sA[im * 64 + ((kb ^ (im & 7)) << 3)];
        }
        #pragma unroll
        for (int jt = 0; jt < 8; ++jt) {
            int jn = jt * 16 + pxl;
            bf16x8 bf = *(const bf16x8*)&sB[jn * 64 + ((kb ^ (jn & 7)) << 3)];
            #pragma unroll
            for (int mt = 0; mt < 2; ++mt)
                acc[mt][jt] = __builtin_amdgcn_mfma_f32_16x16x32_bf16(af[mt], bf, acc[mt][jt], 0, 0, 0);
        }
    }
}

// stage 128 rows x 64 k (k-step Q) from global [row][k] (k contiguous)
#define STAGE_DIRECT64(sDst, ROWADDR, Q)                                     \
    {   uint32_t* s32_ = (uint32_t*)(sDst);                                  \
        _Pragma("unroll")                                                    \
        for (int it_ = 0; it_ < 8; ++it_) {                                  \
            int idx_ = tid + it_ * 256;                                      \
            int il_ = idx_ >> 4, k_ = (idx_ & 15) * 4;                       \
            float4 v_ = *(const float4*)(ROWADDR(il_) + (Q) * 64 + k_);      \
            uint32_t p0_ = (uint32_t)f2bf(v_.x) | ((uint32_t)f2bf(v_.y) << 16); \
            uint32_t p1_ = (uint32_t)f2bf(v_.z) | ((uint32_t)f2bf(v_.w) << 16); \
            int off_ = il_ * 64 + ((((k_ >> 3) ^ (il_ & 7)) << 3) | (k_ & 7)); \
            s32_[off_ >> 1] = p0_;                                           \
            s32_[(off_ >> 1) + 1] = p1_;                                     \
        }                                                                    \
    }

// stage 128 rows x 64 k (k-step Q) from global [k][row] (row contiguous):
// float4 along row dim, scattered ushort LDS writes (transpose).
#define STAGE_TRANS64(sDst, KROWADDR, Q)                                     \
    {   _Pragma("unroll")                                                    \
        for (int it_ = 0; it_ < 8; ++it_) {                                  \
            int idx_ = tid + it_ * 256;                                      \
            int r_ = idx_ >> 5, il4_ = (idx_ & 31) * 4;                      \
            float4 v_ = *(const float4*)(KROWADDR((Q) * 64 + r_) + il4_);    \
            float vv_[4] = {v_.x, v_.y, v_.z, v_.w};                         \
            int kb_ = r_ >> 3;                                               \
            _Pragma("unroll")                                                \
            for (int e_ = 0; e_ < 4; ++e_) {                                 \
                int il_ = il4_ + e_;                                         \
                (sDst)[il_ * 64 + (((kb_ ^ (il_ & 7)) << 3) | (r_ & 7))] = f2bf(vv_[e_]); \
            }                                                                \
        }                                                                    \
    }

// ---- attention logits partials: part[ks][i][j], K-dim = h (wxw) / w (hxh) --
template<bool HXH>
__global__ __launch_bounds__(256) void attn_logits_mfma(const float* __restrict__ dw_,
        float* __restrict__ part_, size_t zd, size_t zp) {
    __shared__ unsigned short sA[128 * 64];
    __shared__ unsigned short sB[128 * 64];
    const float* dw = dw_ + (size_t)blockIdx.z * zd;
    float* part = part_ + (size_t)blockIdx.z * zp;
    int tid = threadIdx.x, lane = tid & 63, wave = tid >> 6;
    int i0 = (blockIdx.x & 1) * 128, j0 = (blockIdx.x >> 1) * 128;
    int ks = blockIdx.y;
    const float* qc = dw + ((size_t)ks << 16);
    const float* kc = dw + ((size_t)(64 + ks) << 16);
    f32x4 acc[2][8];
    #pragma unroll
    for (int mt = 0; mt < 2; ++mt)
        #pragma unroll
        for (int jt = 0; jt < 8; ++jt) acc[mt][jt] = (f32x4){0.f, 0.f, 0.f, 0.f};
    for (int q = 0; q < 4; ++q) {
        if (q) __syncthreads();              // prior compute reads done
        if constexpr (HXH) {
            #define ROWA_Q(il) (qc + (size_t)(i0 + (il)) * 256)
            #define ROWA_K(il) (kc + (size_t)(j0 + (il)) * 256)
            STAGE_DIRECT64(sA, ROWA_Q, q)
            STAGE_DIRECT64(sB, ROWA_K, q)
            #undef ROWA_Q
            #undef ROWA_K
        } else {
            #define KROW_Q(r) (qc + (size_t)(r) * 256 + i0)
            #define KROW_K(r) (kc + (size_t)(r) * 256 + j0)
            STAGE_TRANS64(sA, KROW_Q, q)
            STAGE_TRANS64(sB, KROW_K, q)
            #undef KROW_Q
            #undef KROW_K
        }
        __syncthreads();
        mfma_step64(sA, sB, wave, lane, acc);
    }
    int pxl = lane & 15, quad = lane >> 4;
    float* pb = part + ((size_t)ks << 16);
    #pragma unroll
    for (int mt = 0; mt < 2; ++mt) {
        #pragma unroll
        for (int jt = 0; jt < 8; ++jt) {
            #pragma unroll
            for (int r = 0; r < 4; ++r) {
                int i = i0 + wave * 32 + mt * 16 + quad * 4 + r;
                int j = j0 + jt * 16 + pxl;
                pb[(size_t)i * 256 + j] = acc[mt][jt][r];
            }
        }
    }
}

// ---- av_w: Out[m=(h,c)][u] = sum_w V[c,h,w] * Att[w,u] ---------------------
__global__ __launch_bounds__(256) void av_w_mfma(const float* __restrict__ dw_,
        const float* __restrict__ att_, float* __restrict__ out_,
        size_t zd, size_t za, size_t zo) {
    __shared__ unsigned short sA[128 * 64];
    __shared__ unsigned short sB[128 * 64];
    const float* dw = dw_ + (size_t)blockIdx.z * zd;
    const float* att = att_ + (size_t)blockIdx.z * za;
    float* out = out_ + (size_t)blockIdx.z * zo;
    int tid = threadIdx.x, lane = tid & 63, wave = tid >> 6;
    int m0 = blockIdx.x * 128, u0 = blockIdx.y * 128;
    f32x4 acc[2][8];
    #pragma unroll
    for (int mt = 0; mt < 2; ++mt)
        #pragma unroll
        for (int jt = 0; jt < 8; ++jt) acc[mt][jt] = (f32x4){0.f, 0.f, 0.f, 0.f};
    for (int q = 0; q < 4; ++q) {
        if (q) __syncthreads();
        #define ROWA_V(il) (dw + ((size_t)(128 + ((m0 + (il)) & 63)) << 16) \
                               + ((m0 + (il)) >> 6) * 256)
        #define KROW_ATT(r) (att + (size_t)(r) * 256 + u0)
        STAGE_DIRECT64(sA, ROWA_V, q)
        STAGE_TRANS64(sB, KROW_ATT, q)
        #undef ROWA_V
        #undef KROW_ATT
        __syncthreads();
        mfma_step64(sA, sB, wave, lane, acc);
    }
    int pxl = lane & 15, quad = lane >> 4;
    #pragma unroll
    for (int mt = 0; mt < 2; ++mt) {
        #pragma unroll
        for (int jt = 0; jt < 8; ++jt) {
            #pragma unroll
            for (int r = 0; r < 4; ++r) {
                int m = m0 + wave * 32 + mt * 16 + quad * 4 + r;
                int c = m & 63, h = m >> 6;
                out[((size_t)c << 16) + h * 256 + u0 + jt * 16 + pxl] = acc[mt][jt][r];
            }
        }
    }
}

// ---- av_h: Out[c][h][w] = sum_g Att[h,g] * V[c,g,w] ------------------------
__global__ __launch_bounds__(256) void av_h_mfma(const float* __restrict__ dw_,
        const float* __restrict__ att_, float* __restrict__ out_,
        size_t zd, size_t za, size_t zo) {
    __shared__ unsigned short sA[128 * 64];
    __shared__ unsigned short sB[128 * 64];
    const float* dw = dw_ + (size_t)blockIdx.z * zd;
    const float* att = att_ + (size_t)blockIdx.z * za;
    float* out = out_ + (size_t)blockIdx.z * zo;
    int tid = threadIdx.x, lane = tid & 63, wave = tid >> 6;
    int c = blockIdx.x >> 1;
    int w0 = (blockIdx.x & 1) * 128;
    int h0 = blockIdx.y * 128;
    const float* vc = dw + ((size_t)(128 + c) << 16);
    f32x4 acc[2][8];
    #pragma unroll
    for (int mt = 0; mt < 2; ++mt)
        #pragma unroll
        for (int jt = 0; jt < 8; ++jt) acc[mt][jt] = (f32x4){0.f, 0.f, 0.f, 0.f};
    for (int q = 0; q < 4; ++q) {
        if (q) __syncthreads();
        #define ROWA_ATT(il) (att + (size_t)(h0 + (il)) * 256)
        #define KROW_V(r) (vc + (size_t)(r) * 256 + w0)
        STAGE_DIRECT64(sA, ROWA_ATT, q)
        STAGE_TRANS64(sB, KROW_V, q)
        #undef ROWA_ATT
        #undef KROW_V
        __syncthreads();
        mfma_step64(sA, sB, wave, lane, acc);
    }
    int pxl = lane & 15, quad = lane >> 4;
    #pragma unroll
    for (int mt = 0; mt < 2; ++mt) {
        #pragma unroll
        for (int jt = 0; jt < 8; ++jt) {
            #pragma unroll
            for (int r = 0; r < 4; ++r) {
                int h = h0 + wave * 32 + mt * 16 + quad * 4 + r;
                out[((size_t)c << 16) + h * 256 + w0 + jt * 16 + pxl] = acc[mt][jt][r];
            }
        }
    }
}

// ---------------- sum 64 K-split partials, scale by temp, softmax row -------
__global__ __launch_bounds__(256) void softmax_kernel(const float* __restrict__ part_,
        const float* __restrict__ temp, float* __restrict__ att_,
        size_t zp, size_t za) {
    const float* part = part_ + (size_t)blockIdx.z * zp;
    float* att = att_ + (size_t)blockIdx.z * za;
    int i = blockIdx.x;
    int j = threadIdx.x;
    size_t rowoff = (size_t)i * 256 + j;
    float s = 0.f;
    #pragma unroll
    for (int kk = 0; kk < 64; ++kk) s += part[(size_t)kk * 65536 + rowoff];
    s *= temp[0];
    __shared__ float redA[4], redB[4];
    int wv = j >> 6, ln = j & 63;
    float m = s;
    #pragma unroll
    for (int off = 32; off; off >>= 1) m = fmaxf(m, __shfl_down(m, off, 64));
    if (ln == 0) redA[wv] = m;
    __syncthreads();
    m = fmaxf(fmaxf(redA[0], redA[1]), fmaxf(redA[2], redA[3]));
    float e = expf(s - m);
    float t2 = e;
    #pragma unroll
    for (int off = 32; off; off >>= 1) t2 += __shfl_down(t2, off, 64);
    if (ln == 0) redB[wv] = t2;
    __syncthreads();
    float tot = redB[0] + redB[1] + redB[2] + redB[3];
    att[rowoff] = e / tot;
}

// ======= wave-per-row depthwise 3x3 + bias, optional L2-norm over w =========
template<bool NORM>
__global__ __launch_bounds__(256) void dw_row_kernel(const float* __restrict__ in_,
        const float* __restrict__ w9, const float* __restrict__ bias,
        float* __restrict__ out_, size_t zi, size_t zo) {
    const float* in = in_ + (size_t)blockIdx.z * zi;
    float* out = out_ + (size_t)blockIdx.z * zo;
    int row = __builtin_amdgcn_readfirstlane(blockIdx.x * 4 + (threadIdx.x >> 6));
    int o = row >> 8, h = row & 255;
    int lane = threadIdx.x & 63;
    const float* ip = in + ((size_t)o << 16);
    const float* wp = w9 + o * 9;
    float b = bias[o];
    float4 acc = make_float4(b, b, b, b);
    #pragma unroll
    for (int dy = -1; dy <= 1; ++dy) {
        int hh = h + dy;
        float4 v = make_float4(0.f, 0.f, 0.f, 0.f);
        if (hh >= 0 && hh <= 255)
            v = *(const float4*)(ip + hh * 256 + lane * 4);
        float lft = __shfl(v.w, lane - 1);
        float rgt = __shfl(v.x, lane + 1);
        if (lane == 0)  lft = 0.f;
        if (lane == 63) rgt = 0.f;
        float w0 = wp[(dy+1)*3], w1 = wp[(dy+1)*3+1], w2 = wp[(dy+1)*3+2];
        acc.x += w0*lft + w1*v.x + w2*v.y;
        acc.y += w0*v.x + w1*v.y + w2*v.z;
        acc.z += w0*v.y + w1*v.z + w2*v.w;
        acc.w += w0*v.z + w1*v.w + w2*rgt;
    }
    if constexpr (NORM) {
        if (o < 128) {   // q,k channels: l2-normalize this w-row
            float s = acc.x*acc.x + acc.y*acc.y + acc.z*acc.z + acc.w*acc.w;
            #pragma unroll
            for (int off = 32; off; off >>= 1) s += __shfl_xor(s, off, 64);
            float inv = 1.0f / fmaxf(sqrtf(s), 1e-12f);
            acc.x *= inv; acc.y *= inv; acc.z *= inv; acc.w *= inv;
        }
    }
    *(float4*)(out + ((size_t)o << 16) + h * 256 + lane * 4) = acc;
}

// ===== wave-per-row FFN depthwise 3x3 pair fused with exact-GELU gate =======
__global__ __launch_bounds__(256) void ffn_dw_row_kernel(const float* __restrict__ hid_,
        const float* __restrict__ w9, const float* __restrict__ bias,
        float* __restrict__ g_, size_t zi, size_t zo) {
    const float* hid = hid_ + (size_t)blockIdx.z * zi;
    float* g = g_ + (size_t)blockIdx.z * zo;
    int row = __builtin_amdgcn_readfirstlane(blockIdx.x * 4 + (threadIdx.x >> 6));
    int i = row >> 8, h = row & 255;
    int lane = threadIdx.x & 63;
    const float* ip1 = hid + ((size_t)i << 16);
    const float* ip2 = ip1 + ((size_t)170 << 16);
    const float* wp1 = w9 + i * 9;
    const float* wp2 = w9 + (i + 170) * 9;
    float ba = bias[i], bb = bias[i + 170];
    float4 a = make_float4(ba, ba, ba, ba);
    float4 c = make_float4(bb, bb, bb, bb);
    #pragma unroll
    for (int dy = -1; dy <= 1; ++dy) {
        int hh = h + dy;
        float4 v1 = make_float4(0.f, 0.f, 0.f, 0.f);
        float4 v2 = make_float4(0.f, 0.f, 0.f, 0.f);
        if (hh >= 0 && hh <= 255) {
            v1 = *(const float4*)(ip1 + hh * 256 + lane * 4);
            v2 = *(const float4*)(ip2 + hh * 256 + lane * 4);
        }
        float l1 = __shfl(v1.w, lane - 1), r1 = __shfl(v1.x, lane + 1);
        float l2 = __shfl(v2.w, lane - 1), r2 = __shfl(v2.x, lane + 1);
        if (lane == 0)  { l1 = 0.f; l2 = 0.f; }
        if (lane == 63) { r1 = 0.f; r2 = 0.f; }
        float u0 = wp1[(dy+1)*3], u1 = wp1[(dy+1)*3+1], u2 = wp1[(dy+1)*3+2];
        float q0 = wp2[(dy+1)*3], q1 = wp2[(dy+1)*3+1], q2 = wp2[(dy+1)*3+2];
        a.x += u0*l1   + u1*v1.x + u2*v1.y;
        a.y += u0*v1.x + u1*v1.y + u2*v1.z;
        a.z += u0*v1.y + u1*v1.z + u2*v1.w;
        a.w += u0*v1.z + u1*v1.w + u2*r1;
        c.x += q0*l2   + q1*v2.x + q2*v2.y;
        c.y += q0*v2.x + q1*v2.y + q2*v2.z;
        c.z += q0*v2.y + q1*v2.z + q2*v2.w;
        c.w += q0*v2.z + q1*v2.w + q2*r2;
    }
    const float ISQ2 = 0.70710678118654752440f;
    float4 r;
    r.x = 0.5f * a.x * (1.0f + erff(a.x * ISQ2)) * c.x;
    r.y = 0.5f * a.y * (1.0f + erff(a.y * ISQ2)) * c.y;
    r.z = 0.5f * a.z * (1.0f + erff(a.z * ISQ2)) * c.z;
    r.w = 0.5f * a.w * (1.0f + erff(a.w * ISQ2)) * c.w;
    *(float4*)(g + ((size_t)i << 16) + h * 256 + lane * 4) = r;
}

// ---------------- l2 normalize over (c,w), per (q|k, h) ---------------------
__global__ __launch_bounds__(256) void l2norm_h_kernel(float* __restrict__ dw_,
        size_t zd) {
    float* dw = dw_ + (size_t)blockIdx.z * zd;
    int h = blockIdx.x, qk = blockIdx.y;
    float* base = dw + ((size_t)(qk*64) << 16) + h*256;
    int tid = threadIdx.x;
    float s = 0.f;
    for (int idx = tid; idx < 16384; idx += 256) {
        int c = idx >> 8, w = idx & 255;
        float v = base[((size_t)c << 16) + w];
        s += v * v;
    }
    #pragma unroll
    for (int off = 32; off; off >>= 1) s += __shfl_down(s, off, 64);
    __shared__ float red[4];
    int wv = tid >> 6, ln = tid & 63;
    if (ln == 0) red[wv] = s;
    __syncthreads();
    float tot = red[0] + red[1] + red[2] + red[3];
    float inv = 1.0f / fmaxf(sqrtf(tot), 1e-12f);
    for (int idx = tid; idx < 16384; idx += 256) {
        int c = idx >> 8, w = idx & 255;
        base[((size_t)c << 16) + w] *= inv;
    }
}

// ---------------------------------------------------------------------------
extern "C" void kernel_launch(void* const* d_in, const int* in_sizes, int n_in,
                              void* d_out, int out_size, void* d_ws, size_t ws_size,
                              hipStream_t stream) {
    (void)in_sizes; (void)n_in; (void)out_size;
    const float* x = (const float*)d_in[0];
    float* ws  = (float*)d_ws;
    float* out = (float*)d_out;
    const size_t XB = (size_t)64 * P_;          // x/out floats per batch
    const size_t SLAB_BYTES = WSB * sizeof(float);
    // how many batches can run concurrently in the workspace?
    int nb = 1;
    if (ws_size >= 4 * SLAB_BYTES) nb = 4;
    else if (ws_size >= 2 * SLAB_BYTES) nb = 2;

    for (int b0 = 0; b0 < 4; b0 += nb) {
        int zc = (4 - b0 < nb) ? (4 - b0) : nb;
        const float* xb = x + (size_t)b0 * XB;
        float* outb = out + (size_t)b0 * XB;
        float* DW   = ws + DW_OFF;
        float* QKV  = ws + QKV_OFF;
        float* ATTP = ws + ATTP_OFF;   // aliases QKV (dead by the time it's used)
        float* Y    = ws + Y_OFF;
        float* ATT  = ws + ATT_OFF;
        float* HID  = ws + HID_OFF;
        float* G    = ws + G_OFF;

        // ===== stage A: attention over W (wxw); m -> d_out =====
        conv_mfma_kernel<64,64,192,192,128,true,false><<<dim3(512,1,zc), 256, 0, stream>>>(
                xb, (const float*)d_in[2], (const float*)d_in[3],
                (const float*)d_in[4], (const float*)d_in[5], QKV, nullptr,
                XB, WSB, 0);
        dw_row_kernel<true><<<dim3(12288,1,zc), 256, 0, stream>>>(QKV,
                (const float*)d_in[6], (const float*)d_in[7], DW, WSB, WSB);
        attn_logits_mfma<false><<<dim3(4,64,zc), 256, 0, stream>>>(DW, ATTP, WSB, WSB);
        softmax_kernel<<<dim3(256,1,zc), 256, 0, stream>>>(ATTP,
                (const float*)d_in[10], ATT, WSB, WSB);
        av_w_mfma<<<dim3(128,2,zc), 256, 0, stream>>>(DW, ATT, Y, WSB, WSB, WSB);
        conv_mfma_kernel<64,64,64,64,128,false,true><<<dim3(512,1,zc), 256, 0, stream>>>(
                Y, nullptr, nullptr,
                (const float*)d_in[8], (const float*)d_in[9], outb, xb,
                WSB, XB, XB);

        // ===== stage B: attention over H (hxh); z -> d_out =====
        conv_mfma_kernel<64,64,192,192,128,true,false><<<dim3(512,1,zc), 256, 0, stream>>>(
                outb, (const float*)d_in[11], (const float*)d_in[12],
                (const float*)d_in[13], (const float*)d_in[14], QKV, nullptr,
                XB, WSB, 0);
        dw_row_kernel<false><<<dim3(12288,1,zc), 256, 0, stream>>>(QKV,
                (const float*)d_in[15], (const float*)d_in[16], DW, WSB, WSB);
        l2norm_h_kernel<<<dim3(256,2,zc), 256, 0, stream>>>(DW, WSB);
        attn_logits_mfma<true><<<dim3(4,64,zc), 256, 0, stream>>>(DW, ATTP, WSB, WSB);
        softmax_kernel<<<dim3(256,1,zc), 256, 0, stream>>>(ATTP,
                (const float*)d_in[19], ATT, WSB, WSB);
        av_h_mfma<<<dim3(128,2,zc), 256, 0, stream>>>(DW, ATT, Y, WSB, WSB, WSB);
        conv_mfma_kernel<64,64,64,64,128,false,true><<<dim3(512,1,zc), 256, 0, stream>>>(
                Y, nullptr, nullptr,
                (const float*)d_in[17], (const float*)d_in[18], outb, outb,
                WSB, XB, XB);

        // ===== stage C: gated FFN; z + ffn -> d_out =====
        conv_mfma_kernel<64,64,340,192,128,true,false><<<dim3(512,2,zc), 256, 0, stream>>>(
                outb, (const float*)d_in[20], (const float*)d_in[21],
                (const float*)d_in[22], (const float*)d_in[23], HID, nullptr,
                XB, WSB, 0);
        ffn_dw_row_kernel<<<dim3(10880,1,zc), 256, 0, stream>>>(HID,
                (const float*)d_in[24], (const float*)d_in[25], G, WSB, WSB);
        conv_mfma_kernel<170,192,64,64,64,false,true><<<dim3(1024,1,zc), 256, 0, stream>>>(
                G, nullptr, nullptr,
                (const float*)d_in[26], (const float*)d_in[27], outb, outb,
                WSB, XB, XB);
    }
}

// Round 6
// 1158.233 us; speedup vs baseline: 1.5839x; 1.1615x over previous
//
#include <hip/hip_runtime.h>
#include <math.h>
#include <stdint.h>

// Problem constants (per batch): C=64, H=W=256, P=65536 pixels.
#define P_ 65536

// ---- per-batch workspace layout (float offsets; bf16 buffers use the same
// ---- regions reinterpreted as ushort, occupying half the reserved bytes).
// ---- Slab = 33,423,360 floats = 127.5 MiB; batches run concurrently via
// ---- blockIdx.z when ws_size holds multiple slabs.
#define DW_OFF   0ul            // 192*P bf16 (q,k,v post-dwconv)
#define QKV_OFF  12582912ul     // 192*P bf16 (pre-dwconv)  [dead after dwconv]
#define ATTP_OFF QKV_OFF        // 64*P fp32 K-split partials ALIAS dead QKV
#define Y_OFF    25165824ul     // 64*P bf16 (attn out)
#define ATT_OFF  31457280ul     // P fp32    (softmaxed attention)
// stage C overlays:
#define HID_OFF  0ul            // 340*P bf16
#define G_OFF    22282240ul     // 170*P bf16
#define WSB      33423360ul     // floats per batch slab

typedef unsigned short ush;
typedef __attribute__((ext_vector_type(8))) short bf16x8;   // 8 bf16 in 4 VGPRs
typedef __attribute__((ext_vector_type(4))) float f32x4;

__device__ __forceinline__ ush f2bf(float f) {   // RNE fp32->bf16
    uint32_t u = __float_as_uint(f);
    return (ush)((u + 0x7FFFu + ((u >> 16) & 1u)) >> 16);
}
__device__ __forceinline__ float bf2f(ush h) {
    return __uint_as_float((uint32_t)h << 16);
}

// ============== MFMA 1x1 conv: out[o,p] = sum_c W[o,c]*X[c,p] ===============
// PX-pixel tile per block, 256 threads = 4 waves. Weight slab of COPAD
// outputs staged once; COUT>COPAD split across gridDim.y (obase).
// A=X (m=pixel), B=W (n=o); D row = pixel, col = o -> float4/ushort4 stores.
// INBF/OUTBF select bf16 global input/output. Zero barriers after staging(+LN).
template<int CIN, int CPAD, int COUT, int COPAD, int PX, bool LN, bool RES,
         bool INBF, bool OUTBF>
__global__ __launch_bounds__(256) void conv_mfma_kernel(
        const void* __restrict__ in_, const float* __restrict__ lnw,
        const float* __restrict__ lnb, const float* __restrict__ Wt,
        const float* __restrict__ bias, void* __restrict__ out_,
        const float* __restrict__ res_, size_t zi, size_t zo, size_t zr) {
    static_assert(!(RES && OUTBF), "res only with fp32 out");
    constexpr int NSL = CPAD / 32;           // K slices of 32
    constexpr int NMT = PX / 16;             // pixel m-tiles
    constexpr bool HOIST = (CPAD == 64 && PX == 128);
    __shared__ ush sX[PX * CPAD];
    __shared__ ush sW[COPAD * CPAD];
    __shared__ float sPa[LN ? 256 : 1], sPb[LN ? 256 : 1];
    __shared__ float sMu[LN ? 128 : 1], sInv[LN ? 128 : 1];
    int tid = threadIdx.x;
    int hw0 = blockIdx.x * PX;
    int obase = blockIdx.y * COPAD;
    int lane = tid & 63, wave = tid >> 6;

    {   // ---- stage X: global -> bf16 swizzled LDS [px][c] ----
        uint32_t* sX32 = (uint32_t*)sX;
        #pragma unroll
        for (int it = 0; it < PX * CPAD / 512; ++it) {
            int idx = tid + it * 256;
            int p = idx & (PX - 1), c = (idx / PX) * 2;
            uint32_t pk;
            if constexpr (INBF) {
                const ush* in = (const ush*)in_ + (size_t)blockIdx.z * zi;
                ush a = (c < CIN)     ? in[(size_t)c * P_ + hw0 + p]     : (ush)0;
                ush b = (c + 1 < CIN) ? in[(size_t)(c+1) * P_ + hw0 + p] : (ush)0;
                pk = (uint32_t)a | ((uint32_t)b << 16);
            } else {
                const float* in = (const float*)in_ + (size_t)blockIdx.z * zi;
                float v0 = (c < CIN)     ? in[(size_t)c * P_ + hw0 + p]     : 0.f;
                float v1 = (c + 1 < CIN) ? in[(size_t)(c+1) * P_ + hw0 + p] : 0.f;
                pk = (uint32_t)f2bf(v0) | ((uint32_t)f2bf(v1) << 16);
            }
            int kb = c >> 3;
            sX32[(p * CPAD + (((kb ^ (p & 7)) << 3) | (c & 7))) >> 1] = pk;
        }
    }
    {   // ---- stage weight slab [obase, obase+COPAD): [o][c] bf16 swizzled --
        uint32_t* sW32 = (uint32_t*)sW;
        #pragma unroll
        for (int it = 0; it < COPAD * CPAD / 512; ++it) {
            int idx = tid + it * 256;
            int c2 = idx % (CPAD / 2), o = idx / (CPAD / 2);
            int c = c2 * 2, og = obase + o;
            float v0 = (og < COUT && c < CIN)     ? Wt[(size_t)og * CIN + c]     : 0.f;
            float v1 = (og < COUT && c + 1 < CIN) ? Wt[(size_t)og * CIN + c + 1] : 0.f;
            uint32_t pk = (uint32_t)f2bf(v0) | ((uint32_t)f2bf(v1) << 16);
            int kb = c >> 3;
            sW32[(o * CPAD + (((kb ^ (o & 7)) << 3) | (c & 7))) >> 1] = pk;
        }
    }
    __syncthreads();
    if constexpr (LN) {                      // per-pixel LN over 64 channels
        static_assert(!LN || (CPAD == 64 && PX == 128), "LN path assumes 64ch/128px");
        int p = tid & 127, q = tid >> 7;     // q in {0,1}: 32 channels each
        float s = 0.f, s2 = 0.f;
        #pragma unroll
        for (int c = q * 32; c < q * 32 + 32; ++c) {
            float v = bf2f(sX[p * 64 + ((((c >> 3) ^ (p & 7)) << 3) | (c & 7))]);
            s += v; s2 += v * v;
        }
        sPa[tid] = s; sPb[tid] = s2;
        __syncthreads();
        if (tid < 128) {
            float ss = sPa[tid] + sPa[tid+128];
            float qq = sPb[tid] + sPb[tid+128];
            float mu = ss * (1.f/64.f);
            float var = qq * (1.f/64.f) - mu * mu;
            sMu[tid] = mu; sInv[tid] = rsqrtf(var + 1e-5f);
        }
        __syncthreads();
        float mu = sMu[p], inv = sInv[p];
        #pragma unroll
        for (int c = q * 32; c < q * 32 + 32; ++c) {
            int sw = p * 64 + ((((c >> 3) ^ (p & 7)) << 3) | (c & 7));
            float v = bf2f(sX[sw]);
            sX[sw] = f2bf((v - mu) * inv * lnw[c] + lnb[c]);
        }
        __syncthreads();
    }

    int pxl = lane & 15, quad = lane >> 4;
    int olim = (COUT - obase < COPAD) ? (COUT - obase) : COPAD;
    int ntile = (olim + 15) >> 4;
    bf16x8 xf[HOIST ? NMT * NSL : 1];        // hoisted X frags (regs)
    if constexpr (HOIST) {
        #pragma unroll
        for (int m = 0; m < NMT; ++m)
            #pragma unroll
            for (int s = 0; s < NSL; ++s) {
                int p = m * 16 + pxl;
                int kb = s * 4 + quad;
                xf[m * NSL + s] = *(const bf16x8*)&sX[p * CPAD + ((kb ^ (p & 7)) << 3)];
            }
    }
    for (int ot = wave; ot < ntile; ot += 4) {
        int on = ot * 16 + pxl;              // lane's o within slab
        int og = obase + on;
        f32x4 acc[NMT];
        #pragma unroll
        for (int m = 0; m < NMT; ++m) acc[m] = (f32x4){0.f, 0.f, 0.f, 0.f};
        #pragma unroll
        for (int s = 0; s < NSL; ++s) {
            int kb = s * 4 + quad;
            bf16x8 wf = *(const bf16x8*)&sW[on * CPAD + ((kb ^ (on & 7)) << 3)];
            #pragma unroll
            for (int m = 0; m < NMT; ++m) {
                bf16x8 af;
                if constexpr (HOIST) af = xf[m * NSL + s];
                else {
                    int p = m * 16 + pxl;
                    af = *(const bf16x8*)&sX[p * CPAD + ((kb ^ (p & 7)) << 3)];
                }
                acc[m] = __builtin_amdgcn_mfma_f32_16x16x32_bf16(af, wf, acc[m], 0, 0, 0);
            }
        }
        bool oval = og < COUT;
        float bv = oval ? bias[og] : 0.f;
        #pragma unroll
        for (int m = 0; m < NMT; ++m) {
            if (oval) {
                size_t ob = (size_t)og * P_ + hw0 + m * 16 + quad * 4;
                if constexpr (OUTBF) {
                    ush* out = (ush*)out_ + (size_t)blockIdx.z * zo;
                    ushort4 sv;
                    sv.x = f2bf(acc[m][0] + bv); sv.y = f2bf(acc[m][1] + bv);
                    sv.z = f2bf(acc[m][2] + bv); sv.w = f2bf(acc[m][3] + bv);
                    *(ushort4*)&out[ob] = sv;
                } else {
                    float* out = (float*)out_ + (size_t)blockIdx.z * zo;
                    float4 v = make_float4(acc[m][0] + bv, acc[m][1] + bv,
                                           acc[m][2] + bv, acc[m][3] + bv);
                    if constexpr (RES) {
                        const float* res = res_ + (size_t)blockIdx.z * zr;
                        float4 rv = *(const float4*)&res[ob];
                        v.x += rv.x; v.y += rv.y; v.z += rv.z; v.w += rv.w;
                    }
                    *(float4*)&out[ob] = v;
                }
            }
        }
    }
}

// ========= MFMA 128x128x256 GEMM core (attn logits / AV products) ==========
// K in 4 sequential 64-steps; per step stage 128x64 bf16 A and B (32 KB LDS).
__device__ __forceinline__ void mfma_step64(const ush* sA,
        const ush* sB, int wave, int lane, f32x4 acc[2][8]) {
    int pxl = lane & 15, quad = lane >> 4;
    #pragma unroll
    for (int s = 0; s < 2; ++s) {
        int kb = s * 4 + quad;
        bf16x8 af[2];
        #pragma unroll
        for (int mt = 0; mt < 2; ++mt) {
            int im = wave * 32 + mt * 16 + pxl;
            af[mt] = *(const bf16x8*)&sA[im * 64 + ((kb ^ (im & 7)) << 3)];
        }
        #pragma unroll
        for (int jt = 0; jt < 8; ++jt) {
            int jn = jt * 16 + pxl;
            bf16x8 bf = *(const bf16x8*)&sB[jn * 64 + ((kb ^ (jn & 7)) << 3)];
            #pragma unroll
            for (int mt = 0; mt < 2; ++mt)
                acc[mt][jt] = __builtin_amdgcn_mfma_f32_16x16x32_bf16(af[mt], bf, acc[mt][jt], 0, 0, 0);
        }
    }
}

// fp32-source staging (att): unchanged from r4/r5
#define STAGE_DIRECT64(sDst, ROWADDR, Q)                                     \
    {   uint32_t* s32_ = (uint32_t*)(sDst);                                  \
        _Pragma("unroll")                                                    \
        for (int it_ = 0; it_ < 8; ++it_) {                                  \
            int idx_ = tid + it_ * 256;                                      \
            int il_ = idx_ >> 4, k_ = (idx_ & 15) * 4;                       \
            float4 v_ = *(const float4*)(ROWADDR(il_) + (Q) * 64 + k_);      \
            uint32_t p0_ = (uint32_t)f2bf(v_.x) | ((uint32_t)f2bf(v_.y) << 16); \
            uint32_t p1_ = (uint32_t)f2bf(v_.z) | ((uint32_t)f2bf(v_.w) << 16); \
            int off_ = il_ * 64 + ((((k_ >> 3) ^ (il_ & 7)) << 3) | (k_ & 7)); \
            s32_[off_ >> 1] = p0_;                                           \
            s32_[(off_ >> 1) + 1] = p1_;                                     \
        }                                                                    \
    }

#define STAGE_TRANS64(sDst, KROWADDR, Q)                                     \
    {   _Pragma("unroll")                                                    \
        for (int it_ = 0; it_ < 8; ++it_) {                                  \
            int idx_ = tid + it_ * 256;                                      \
            int r_ = idx_ >> 5, il4_ = (idx_ & 31) * 4;                      \
            float4 v_ = *(const float4*)(KROWADDR((Q) * 64 + r_) + il4_);    \
            float vv_[4] = {v_.x, v_.y, v_.z, v_.w};                         \
            int kb_ = r_ >> 3;                                               \
            _Pragma("unroll")                                                \
            for (int e_ = 0; e_ < 4; ++e_) {                                 \
                int il_ = il4_ + e_;                                         \
                (sDst)[il_ * 64 + (((kb_ ^ (il_ & 7)) << 3) | (r_ & 7))] = f2bf(vv_[e_]); \
            }                                                                \
        }                                                                    \
    }

// bf16-source staging: raw ushort4 copies (no conversion)
#define STAGE_DIRECT64_BF(sDst, ROWADDR, Q)                                  \
    {   _Pragma("unroll")                                                    \
        for (int it_ = 0; it_ < 8; ++it_) {                                  \
            int idx_ = tid + it_ * 256;                                      \
            int il_ = idx_ >> 4, k_ = (idx_ & 15) * 4;                       \
            ushort4 v_ = *(const ushort4*)(ROWADDR(il_) + (Q) * 64 + k_);    \
            int off_ = il_ * 64 + ((((k_ >> 3) ^ (il_ & 7)) << 3) | (k_ & 7)); \
            *(ushort4*)&(sDst)[off_] = v_;                                   \
        }                                                                    \
    }

#define STAGE_TRANS64_BF(sDst, KROWADDR, Q)                                  \
    {   _Pragma("unroll")                                                    \
        for (int it_ = 0; it_ < 8; ++it_) {                                  \
            int idx_ = tid + it_ * 256;                                      \
            int r_ = idx_ >> 5, il4_ = (idx_ & 31) * 4;                      \
            ushort4 v_ = *(const ushort4*)(KROWADDR((Q) * 64 + r_) + il4_);  \
            ush vv_[4] = {v_.x, v_.y, v_.z, v_.w};                          \
            int kb_ = r_ >> 3;                                               \
            _Pragma("unroll")                                                \
            for (int e_ = 0; e_ < 4; ++e_) {                                 \
                int il_ = il4_ + e_;                                         \
                (sDst)[il_ * 64 + (((kb_ ^ (il_ & 7)) << 3) | (r_ & 7))] = vv_[e_]; \
            }                                                                \
        }                                                                    \
    }

// ---- attention logits partials: part[ks][i][j] (fp32 out); dw is bf16 ------
template<bool HXH>
__global__ __launch_bounds__(256) void attn_logits_mfma(const ush* __restrict__ dw_,
        float* __restrict__ part_, size_t zd, size_t zp) {
    __shared__ ush sA[128 * 64];
    __shared__ ush sB[128 * 64];
    const ush* dw = dw_ + (size_t)blockIdx.z * zd;
    float* part = part_ + (size_t)blockIdx.z * zp;
    int tid = threadIdx.x, lane = tid & 63, wave = tid >> 6;
    int i0 = (blockIdx.x & 1) * 128, j0 = (blockIdx.x >> 1) * 128;
    int ks = blockIdx.y;
    const ush* qc = dw + ((size_t)ks << 16);
    const ush* kc = dw + ((size_t)(64 + ks) << 16);
    f32x4 acc[2][8];
    #pragma unroll
    for (int mt = 0; mt < 2; ++mt)
        #pragma unroll
        for (int jt = 0; jt < 8; ++jt) acc[mt][jt] = (f32x4){0.f, 0.f, 0.f, 0.f};
    for (int q = 0; q < 4; ++q) {
        if (q) __syncthreads();              // prior compute reads done
        if constexpr (HXH) {
            #define ROWA_Q(il) (qc + (size_t)(i0 + (il)) * 256)
            #define ROWA_K(il) (kc + (size_t)(j0 + (il)) * 256)
            STAGE_DIRECT64_BF(sA, ROWA_Q, q)
            STAGE_DIRECT64_BF(sB, ROWA_K, q)
            #undef ROWA_Q
            #undef ROWA_K
        } else {
            #define KROW_Q(r) (qc + (size_t)(r) * 256 + i0)
            #define KROW_K(r) (kc + (size_t)(r) * 256 + j0)
            STAGE_TRANS64_BF(sA, KROW_Q, q)
            STAGE_TRANS64_BF(sB, KROW_K, q)
            #undef KROW_Q
            #undef KROW_K
        }
        __syncthreads();
        mfma_step64(sA, sB, wave, lane, acc);
    }
    int pxl = lane & 15, quad = lane >> 4;
    float* pb = part + ((size_t)ks << 16);
    #pragma unroll
    for (int mt = 0; mt < 2; ++mt) {
        #pragma unroll
        for (int jt = 0; jt < 8; ++jt) {
            #pragma unroll
            for (int r = 0; r < 4; ++r) {
                int i = i0 + wave * 32 + mt * 16 + quad * 4 + r;
                int j = j0 + jt * 16 + pxl;
                pb[(size_t)i * 256 + j] = acc[mt][jt][r];
            }
        }
    }
}

// ---- av_w: Out[m=(h,c)][u] = sum_w V[c,h,w] * Att[w,u]; V,out bf16 ---------
__global__ __launch_bounds__(256) void av_w_mfma(const ush* __restrict__ dw_,
        const float* __restrict__ att_, ush* __restrict__ out_,
        size_t zd, size_t za, size_t zo) {
    __shared__ ush sA[128 * 64];
    __shared__ ush sB[128 * 64];
    const ush* dw = dw_ + (size_t)blockIdx.z * zd;
    const float* att = att_ + (size_t)blockIdx.z * za;
    ush* out = out_ + (size_t)blockIdx.z * zo;
    int tid = threadIdx.x, lane = tid & 63, wave = tid >> 6;
    int m0 = blockIdx.x * 128, u0 = blockIdx.y * 128;
    f32x4 acc[2][8];
    #pragma unroll
    for (int mt = 0; mt < 2; ++mt)
        #pragma unroll
        for (int jt = 0; jt < 8; ++jt) acc[mt][jt] = (f32x4){0.f, 0.f, 0.f, 0.f};
    for (int q = 0; q < 4; ++q) {
        if (q) __syncthreads();
        #define ROWA_V(il) (dw + ((size_t)(128 + ((m0 + (il)) & 63)) << 16) \
                               + ((m0 + (il)) >> 6) * 256)
        #define KROW_ATT(r) (att + (size_t)(r) * 256 + u0)
        STAGE_DIRECT64_BF(sA, ROWA_V, q)
        STAGE_TRANS64(sB, KROW_ATT, q)
        #undef ROWA_V
        #undef KROW_ATT
        __syncthreads();
        mfma_step64(sA, sB, wave, lane, acc);
    }
    int pxl = lane & 15, quad = lane >> 4;
    #pragma unroll
    for (int mt = 0; mt < 2; ++mt) {
        #pragma unroll
        for (int jt = 0; jt < 8; ++jt) {
            #pragma unroll
            for (int r = 0; r < 4; ++r) {
                int m = m0 + wave * 32 + mt * 16 + quad * 4 + r;
                int c = m & 63, h = m >> 6;
                out[((size_t)c << 16) + h * 256 + u0 + jt * 16 + pxl] = f2bf(acc[mt][jt][r]);
            }
        }
    }
}

// ---- av_h: Out[c][h][w] = sum_g Att[h,g] * V[c,g,w]; V,out bf16 ------------
__global__ __launch_bounds__(256) void av_h_mfma(const ush* __restrict__ dw_,
        const float* __restrict__ att_, ush* __restrict__ out_,
        size_t zd, size_t za, size_t zo) {
    __shared__ ush sA[128 * 64];
    __shared__ ush sB[128 * 64];
    const ush* dw = dw_ + (size_t)blockIdx.z * zd;
    const float* att = att_ + (size_t)blockIdx.z * za;
    ush* out = out_ + (size_t)blockIdx.z * zo;
    int tid = threadIdx.x, lane = tid & 63, wave = tid >> 6;
    int c = blockIdx.x >> 1;
    int w0 = (blockIdx.x & 1) * 128;
    int h0 = blockIdx.y * 128;
    const ush* vc = dw + ((size_t)(128 + c) << 16);
    f32x4 acc[2][8];
    #pragma unroll
    for (int mt = 0; mt < 2; ++mt)
        #pragma unroll
        for (int jt = 0; jt < 8; ++jt) acc[mt][jt] = (f32x4){0.f, 0.f, 0.f, 0.f};
    for (int q = 0; q < 4; ++q) {
        if (q) __syncthreads();
        #define ROWA_ATT(il) (att + (size_t)(h0 + (il)) * 256)
        #define KROW_V(r) (vc + (size_t)(r) * 256 + w0)
        STAGE_DIRECT64(sA, ROWA_ATT, q)
        STAGE_TRANS64_BF(sB, KROW_V, q)
        #undef ROWA_ATT
        #undef KROW_V
        __syncthreads();
        mfma_step64(sA, sB, wave, lane, acc);
    }
    int pxl = lane & 15, quad = lane >> 4;
    #pragma unroll
    for (int mt = 0; mt < 2; ++mt) {
        #pragma unroll
        for (int jt = 0; jt < 8; ++jt) {
            #pragma unroll
            for (int r = 0; r < 4; ++r) {
                int h = h0 + wave * 32 + mt * 16 + quad * 4 + r;
                out[((size_t)c << 16) + h * 256 + w0 + jt * 16 + pxl] = f2bf(acc[mt][jt][r]);
            }
        }
    }
}

// ---------------- sum 64 K-split partials, scale by temp, softmax row -------
__global__ __launch_bounds__(256) void softmax_kernel(const float* __restrict__ part_,
        const float* __restrict__ temp, float* __restrict__ att_,
        size_t zp, size_t za) {
    const float* part = part_ + (size_t)blockIdx.z * zp;
    float* att = att_ + (size_t)blockIdx.z * za;
    int i = blockIdx.x;
    int j = threadIdx.x;
    size_t rowoff = (size_t)i * 256 + j;
    float s = 0.f;
    #pragma unroll
    for (int kk = 0; kk < 64; ++kk) s += part[(size_t)kk * 65536 + rowoff];
    s *= temp[0];
    __shared__ float redA[4], redB[4];
    int wv = j >> 6, ln = j & 63;
    float m = s;
    #pragma unroll
    for (int off = 32; off; off >>= 1) m = fmaxf(m, __shfl_down(m, off, 64));
    if (ln == 0) redA[wv] = m;
    __syncthreads();
    m = fmaxf(fmaxf(redA[0], redA[1]), fmaxf(redA[2], redA[3]));
    float e = expf(s - m);
    float t2 = e;
    #pragma unroll
    for (int off = 32; off; off >>= 1) t2 += __shfl_down(t2, off, 64);
    if (ln == 0) redB[wv] = t2;
    __syncthreads();
    float tot = redB[0] + redB[1] + redB[2] + redB[3];
    att[rowoff] = e / tot;
}

// ======= wave-per-row depthwise 3x3 + bias, optional L2-norm over w =========
// bf16 in (QKV), bf16 out (DW). One wave per (o,h) row: 64 lanes x 4 px.
template<bool NORM>
__global__ __launch_bounds__(256) void dw_row_kernel(const ush* __restrict__ in_,
        const float* __restrict__ w9, const float* __restrict__ bias,
        ush* __restrict__ out_, size_t zi, size_t zo) {
    const ush* in = in_ + (size_t)blockIdx.z * zi;
    ush* out = out_ + (size_t)blockIdx.z * zo;
    int row = __builtin_amdgcn_readfirstlane(blockIdx.x * 4 + (threadIdx.x >> 6));
    int o = row >> 8, h = row & 255;
    int lane = threadIdx.x & 63;
    const ush* ip = in + ((size_t)o << 16);
    const float* wp = w9 + o * 9;
    float b = bias[o];
    float4 acc = make_float4(b, b, b, b);
    #pragma unroll
    for (int dy = -1; dy <= 1; ++dy) {
        int hh = h + dy;
        float4 v = make_float4(0.f, 0.f, 0.f, 0.f);
        if (hh >= 0 && hh <= 255) {
            ushort4 t = *(const ushort4*)(ip + hh * 256 + lane * 4);
            v = make_float4(bf2f(t.x), bf2f(t.y), bf2f(t.z), bf2f(t.w));
        }
        float lft = __shfl(v.w, lane - 1);
        float rgt = __shfl(v.x, lane + 1);
        if (lane == 0)  lft = 0.f;
        if (lane == 63) rgt = 0.f;
        float w0 = wp[(dy+1)*3], w1 = wp[(dy+1)*3+1], w2 = wp[(dy+1)*3+2];
        acc.x += w0*lft + w1*v.x + w2*v.y;
        acc.y += w0*v.x + w1*v.y + w2*v.z;
        acc.z += w0*v.y + w1*v.z + w2*v.w;
        acc.w += w0*v.z + w1*v.w + w2*rgt;
    }
    if constexpr (NORM) {
        if (o < 128) {   // q,k channels: l2-normalize this w-row
            float s = acc.x*acc.x + acc.y*acc.y + acc.z*acc.z + acc.w*acc.w;
            #pragma unroll
            for (int off = 32; off; off >>= 1) s += __shfl_xor(s, off, 64);
            float inv = 1.0f / fmaxf(sqrtf(s), 1e-12f);
            acc.x *= inv; acc.y *= inv; acc.z *= inv; acc.w *= inv;
        }
    }
    ushort4 s4;
    s4.x = f2bf(acc.x); s4.y = f2bf(acc.y); s4.z = f2bf(acc.z); s4.w = f2bf(acc.w);
    *(ushort4*)(out + ((size_t)o << 16) + h * 256 + lane * 4) = s4;
}

// ===== wave-per-row FFN depthwise 3x3 pair fused with exact-GELU gate =======
// bf16 in (HID), bf16 out (G).
__global__ __launch_bounds__(256) void ffn_dw_row_kernel(const ush* __restrict__ hid_,
        const float* __restrict__ w9, const float* __restrict__ bias,
        ush* __restrict__ g_, size_t zi, size_t zo) {
    const ush* hid = hid_ + (size_t)blockIdx.z * zi;
    ush* g = g_ + (size_t)blockIdx.z * zo;
    int row = __builtin_amdgcn_readfirstlane(blockIdx.x * 4 + (threadIdx.x >> 6));
    int i = row >> 8, h = row & 255;
    int lane = threadIdx.x & 63;
    const ush* ip1 = hid + ((size_t)i << 16);
    const ush* ip2 = ip1 + ((size_t)170 << 16);
    const float* wp1 = w9 + i * 9;
    const float* wp2 = w9 + (i + 170) * 9;
    float ba = bias[i], bb = bias[i + 170];
    float4 a = make_float4(ba, ba, ba, ba);
    float4 c = make_float4(bb, bb, bb, bb);
    #pragma unroll
    for (int dy = -1; dy <= 1; ++dy) {
        int hh = h + dy;
        float4 v1 = make_float4(0.f, 0.f, 0.f, 0.f);
        float4 v2 = make_float4(0.f, 0.f, 0.f, 0.f);
        if (hh >= 0 && hh <= 255) {
            ushort4 t1 = *(const ushort4*)(ip1 + hh * 256 + lane * 4);
            ushort4 t2 = *(const ushort4*)(ip2 + hh * 256 + lane * 4);
            v1 = make_float4(bf2f(t1.x), bf2f(t1.y), bf2f(t1.z), bf2f(t1.w));
            v2 = make_float4(bf2f(t2.x), bf2f(t2.y), bf2f(t2.z), bf2f(t2.w));
        }
        float l1 = __shfl(v1.w, lane - 1), r1 = __shfl(v1.x, lane + 1);
        float l2 = __shfl(v2.w, lane - 1), r2 = __shfl(v2.x, lane + 1);
        if (lane == 0)  { l1 = 0.f; l2 = 0.f; }
        if (lane == 63) { r1 = 0.f; r2 = 0.f; }
        float u0 = wp1[(dy+1)*3], u1 = wp1[(dy+1)*3+1], u2 = wp1[(dy+1)*3+2];
        float q0 = wp2[(dy+1)*3], q1 = wp2[(dy+1)*3+1], q2 = wp2[(dy+1)*3+2];
        a.x += u0*l1   + u1*v1.x + u2*v1.y;
        a.y += u0*v1.x + u1*v1.y + u2*v1.z;
        a.z += u0*v1.y + u1*v1.z + u2*v1.w;
        a.w += u0*v1.z + u1*v1.w + u2*r1;
        c.x += q0*l2   + q1*v2.x + q2*v2.y;
        c.y += q0*v2.x + q1*v2.y + q2*v2.z;
        c.z += q0*v2.y + q1*v2.z + q2*v2.w;
        c.w += q0*v2.z + q1*v2.w + q2*r2;
    }
    const float ISQ2 = 0.70710678118654752440f;
    ushort4 s4;
    s4.x = f2bf(0.5f * a.x * (1.0f + erff(a.x * ISQ2)) * c.x);
    s4.y = f2bf(0.5f * a.y * (1.0f + erff(a.y * ISQ2)) * c.y);
    s4.z = f2bf(0.5f * a.z * (1.0f + erff(a.z * ISQ2)) * c.z);
    s4.w = f2bf(0.5f * a.w * (1.0f + erff(a.w * ISQ2)) * c.w);
    *(ushort4*)(g + ((size_t)i << 16) + h * 256 + lane * 4) = s4;
}

// ---------------- l2 normalize over (c,w), per (q|k, h); bf16 in place ------
__global__ __launch_bounds__(256) void l2norm_h_kernel(ush* __restrict__ dw_,
        size_t zd) {
    ush* dw = dw_ + (size_t)blockIdx.z * zd;
    int h = blockIdx.x, qk = blockIdx.y;
    ush* base = dw + ((size_t)(qk*64) << 16) + h*256;
    int tid = threadIdx.x;
    float s = 0.f;
    for (int idx = tid; idx < 4096; idx += 256) {
        int c = idx >> 6, w4 = (idx & 63) * 4;
        ushort4 t = *(const ushort4*)&base[((size_t)c << 16) + w4];
        float a = bf2f(t.x), b = bf2f(t.y), cc = bf2f(t.z), d = bf2f(t.w);
        s += a*a + b*b + cc*cc + d*d;
    }
    #pragma unroll
    for (int off = 32; off; off >>= 1) s += __shfl_down(s, off, 64);
    __shared__ float red[4];
    int wv = tid >> 6, ln = tid & 63;
    if (ln == 0) red[wv] = s;
    __syncthreads();
    float tot = red[0] + red[1] + red[2] + red[3];
    float inv = 1.0f / fmaxf(sqrtf(tot), 1e-12f);
    for (int idx = tid; idx < 4096; idx += 256) {
        int c = idx >> 6, w4 = (idx & 63) * 4;
        ushort4 t = *(const ushort4*)&base[((size_t)c << 16) + w4];
        ushort4 o;
        o.x = f2bf(bf2f(t.x) * inv); o.y = f2bf(bf2f(t.y) * inv);
        o.z = f2bf(bf2f(t.z) * inv); o.w = f2bf(bf2f(t.w) * inv);
        *(ushort4*)&base[((size_t)c << 16) + w4] = o;
    }
}

// ---------------------------------------------------------------------------
extern "C" void kernel_launch(void* const* d_in, const int* in_sizes, int n_in,
                              void* d_out, int out_size, void* d_ws, size_t ws_size,
                              hipStream_t stream) {
    (void)in_sizes; (void)n_in; (void)out_size;
    const float* x = (const float*)d_in[0];
    float* ws  = (float*)d_ws;
    float* out = (float*)d_out;
    const size_t XB = (size_t)64 * P_;          // x/out floats per batch
    const size_t WSB2 = 2 * WSB;                // slab stride in ushorts
    const size_t SLAB_BYTES = WSB * sizeof(float);
    int nb = 1;
    if (ws_size >= 4 * SLAB_BYTES) nb = 4;
    else if (ws_size >= 2 * SLAB_BYTES) nb = 2;

    for (int b0 = 0; b0 < 4; b0 += nb) {
        int zc = (4 - b0 < nb) ? (4 - b0) : nb;
        const float* xb = x + (size_t)b0 * XB;
        float* outb = out + (size_t)b0 * XB;
        ush*   DW   = (ush*)(ws + DW_OFF);
        ush*   QKV  = (ush*)(ws + QKV_OFF);
        float* ATTP = ws + ATTP_OFF;   // aliases QKV (dead by the time it's used)
        ush*   Y    = (ush*)(ws + Y_OFF);
        float* ATT  = ws + ATT_OFF;
        ush*   HID  = (ush*)(ws + HID_OFF);
        ush*   G    = (ush*)(ws + G_OFF);

        // ===== stage A: attention over W (wxw); m -> d_out =====
        conv_mfma_kernel<64,64,192,128,128,true,false,false,true>
            <<<dim3(512,2,zc), 256, 0, stream>>>(
                xb, (const float*)d_in[2], (const float*)d_in[3],
                (const float*)d_in[4], (const float*)d_in[5], QKV, nullptr,
                XB, WSB2, 0);
        dw_row_kernel<true><<<dim3(12288,1,zc), 256, 0, stream>>>(QKV,
                (const float*)d_in[6], (const float*)d_in[7], DW, WSB2, WSB2);
        attn_logits_mfma<false><<<dim3(4,64,zc), 256, 0, stream>>>(DW, ATTP, WSB2, WSB);
        softmax_kernel<<<dim3(256,1,zc), 256, 0, stream>>>(ATTP,
                (const float*)d_in[10], ATT, WSB, WSB);
        av_w_mfma<<<dim3(128,2,zc), 256, 0, stream>>>(DW, ATT, Y, WSB2, WSB, WSB2);
        conv_mfma_kernel<64,64,64,64,128,false,true,true,false>
            <<<dim3(512,1,zc), 256, 0, stream>>>(
                Y, nullptr, nullptr,
                (const float*)d_in[8], (const float*)d_in[9], outb, xb,
                WSB2, XB, XB);

        // ===== stage B: attention over H (hxh); z -> d_out =====
        conv_mfma_kernel<64,64,192,128,128,true,false,false,true>
            <<<dim3(512,2,zc), 256, 0, stream>>>(
                outb, (const float*)d_in[11], (const float*)d_in[12],
                (const float*)d_in[13], (const float*)d_in[14], QKV, nullptr,
                XB, WSB2, 0);
        dw_row_kernel<false><<<dim3(12288,1,zc), 256, 0, stream>>>(QKV,
                (const float*)d_in[15], (const float*)d_in[16], DW, WSB2, WSB2);
        l2norm_h_kernel<<<dim3(256,2,zc), 256, 0, stream>>>(DW, WSB2);
        attn_logits_mfma<true><<<dim3(4,64,zc), 256, 0, stream>>>(DW, ATTP, WSB2, WSB);
        softmax_kernel<<<dim3(256,1,zc), 256, 0, stream>>>(ATTP,
                (const float*)d_in[19], ATT, WSB, WSB);
        av_h_mfma<<<dim3(128,2,zc), 256, 0, stream>>>(DW, ATT, Y, WSB2, WSB, WSB2);
        conv_mfma_kernel<64,64,64,64,128,false,true,true,false>
            <<<dim3(512,1,zc), 256, 0, stream>>>(
                Y, nullptr, nullptr,
                (const float*)d_in[17], (const float*)d_in[18], outb, outb,
                WSB2, XB, XB);

        // ===== stage C: gated FFN; z + ffn -> d_out =====
        conv_mfma_kernel<64,64,340,128,128,true,false,false,true>
            <<<dim3(512,3,zc), 256, 0, stream>>>(
                outb, (const float*)d_in[20], (const float*)d_in[21],
                (const float*)d_in[22], (const float*)d_in[23], HID, nullptr,
                XB, WSB2, 0);
        ffn_dw_row_kernel<<<dim3(10880,1,zc), 256, 0, stream>>>(HID,
                (const float*)d_in[24], (const float*)d_in[25], G, WSB2, WSB2);
        conv_mfma_kernel<170,192,64,64,64,false,true,true,false>
            <<<dim3(1024,1,zc), 256, 0, stream>>>(
                G, nullptr, nullptr,
                (const float*)d_in[26], (const float*)d_in[27], outb, outb,
                WSB2, XB, XB);
    }
}